// Round 6
// baseline (552.745 us; speedup 1.0000x reference)
//
#include <hip/hip_runtime.h>
#include <hip/hip_bf16.h>
#include <hip/hip_fp16.h>
#include <math.h>

#define NF     128
#define HID    6
#define NC     10
#define NG     64
#define SLOTS  64     // ELL row capacity (deg ~ Poisson(32); P(deg>64) ~ 4e-7/node)
#define OVFCAP 8192

// v6: direct ELL build. The two-phase bucket pipeline (scatter->bucket_arr->ell_build)
// cost ~75us combined at an all-idle latency floor (VALU<4%, HBM<13% across r0-r5).
// One kernel with per-edge global atomicAdd(&cnt[dst]) + 4B scatter into ell deletes
// bucket_arr (12.8MB x2 traffic), the LDS stage, 5 barriers, and the whole second kernel.
// ell (25.6MB) ~fits aggregate L2 so random 4B writes ~= one writeback per line (r2
// proved the pattern survivable). Pads handled by per-element clamp in the gather
// (VALU is idle); dinv folded into layer1.

// g row: 6 values as fp16, padded to 16B (8 halves) -> ONE dwordx4 per neighbor.
__device__ __forceinline__ void addh2(__half2& a0, __half2& a1, __half2& a2, uint4 q) {
    const __half2* h = (const __half2*)&q;
    a0 = __hadd2(a0, h[0]);
    a1 = __hadd2(a1, h[1]);
    a2 = __hadd2(a2, h[2]);
}

__device__ __forceinline__ __half2 shfl_xor_h2(__half2 v, int m) {
    union { __half2 h; unsigned int u; } a;
    a.h = v;
    a.u = __shfl_xor(a.u, m);
    return a.h;
}

__device__ __forceinline__ uint4 packh(const float* v) {
    uint4 q;
    __half2* h = (__half2*)&q;
    h[0] = __floats2half2_rn(v[0], v[1]);
    h[1] = __floats2half2_rn(v[2], v[3]);
    h[2] = __floats2half2_rn(v[4], v[5]);
    h[3] = __floats2half2_rn(0.f, 0.f);
    return q;
}

// ---------------- phase 1 (only phase): per-edge atomic slot + direct ELL scatter ----------------
__global__ __launch_bounds__(256) void edge_scatter_kernel(
        const int* __restrict__ src, const int* __restrict__ dst, int E,
        int* __restrict__ cnt, int* __restrict__ ell,
        int* __restrict__ ovf_meta, int* __restrict__ ovf_dst, int* __restrict__ ovf_src) {
    int t = blockIdx.x * 256 + threadIdx.x;
    int stride = gridDim.x * 256;
    int nq = E >> 2;
    const int4* s4 = (const int4*)src;
    const int4* d4 = (const int4*)dst;
    for (int q = t; q < nq; q += stride) {
        int4 sv = s4[q];
        int4 dv = d4[q];
        int ss[4] = { sv.x, sv.y, sv.z, sv.w };
        int dd[4] = { dv.x, dv.y, dv.z, dv.w };
#pragma unroll
        for (int k = 0; k < 4; ++k) {
            int d = dd[k];
            int slot = atomicAdd(&cnt[d], 1);
            if (slot < SLOTS) {
                ell[(size_t)d * SLOTS + slot] = ss[k];
            } else {   // degree overflow (~never)
                int p = atomicAdd(ovf_meta, 1);
                if (p < OVFCAP) { ovf_dst[p] = d; ovf_src[p] = ss[k]; }
            }
        }
    }
    for (int e = (nq << 2) + t; e < E; e += stride) {   // tail (E % 4)
        int d = dst[e];
        int s = src[e];
        int slot = atomicAdd(&cnt[d], 1);
        if (slot < SLOTS) {
            ell[(size_t)d * SLOTS + slot] = s;
        } else {
            int p = atomicAdd(ovf_meta, 1);
            if (p < OVFCAP) { ovf_dst[p] = d; ovf_src[p] = s; }
        }
    }
}

// ---------------- layer 1: g = dinv * (x @ W1), 8 lanes per node; also derives dinv from cnt ----------------
__global__ __launch_bounds__(256) void layer1_kernel(const float* __restrict__ x,
                                                     const float* __restrict__ W,
                                                     const int* __restrict__ cnt,
                                                     float* __restrict__ dinv,
                                                     uint4* __restrict__ g16, int N) {
    __shared__ float sW[8 * 100];
    for (int idx = threadIdx.x; idx < NF * HID; idx += 256) {
        int s = idx / 96, r = idx % 96;
        int o = r / 16, j = r % 16;
        sW[s * 100 + o * 16 + j] = W[(s * 16 + j) * HID + o];
    }
    __syncthreads();
    int t = blockIdx.x * 256 + threadIdx.x;
    int i = t >> 3;
    int sub = t & 7;
    if (t == 0) g16[N] = make_uint4(0u, 0u, 0u, 0u);    // zero row for clamped pads
    if (i >= N) return;
    const float4* xr = (const float4*)(x + (size_t)i * NF + sub * 16);
    float4 xv0 = xr[0], xv1 = xr[1], xv2 = xr[2], xv3 = xr[3];
    const float4* wr = (const float4*)(sW + sub * 100);
    float p[HID];
#pragma unroll
    for (int o = 0; o < HID; ++o) {
        float4 w0 = wr[o * 4 + 0], w1 = wr[o * 4 + 1], w2 = wr[o * 4 + 2], w3 = wr[o * 4 + 3];
        p[o] = xv0.x * w0.x + xv0.y * w0.y + xv0.z * w0.z + xv0.w * w0.w
             + xv1.x * w1.x + xv1.y * w1.y + xv1.z * w1.z + xv1.w * w1.w
             + xv2.x * w2.x + xv2.y * w2.y + xv2.z * w2.z + xv2.w * w2.w
             + xv3.x * w3.x + xv3.y * w3.y + xv3.z * w3.z + xv3.w * w3.w;
    }
#pragma unroll
    for (int m = 1; m < 8; m <<= 1) {
#pragma unroll
        for (int o = 0; o < HID; ++o) p[o] += __shfl_xor(p[o], m);
    }
    if (sub == 0) {
        float dv = rsqrtf((float)cnt[i] + 1.0f);   // +1 self loop; fused from old ell_build
        dinv[i] = dv;
        float v[HID];
#pragma unroll
        for (int o = 0; o < HID; ++o) v[o] = dv * p[o];
        g16[i] = packh(v);
    }
}

// ---------------- chunked ELL gather (fp16 rows, fp16 accumulate, clamped pads) ----------------
// sub-lane owns chunk [4*sub,4*sub+4) then [32+4*sub,...). Slots >= ne are clamped to the
// zero row at index N (ell beyond cnt holds workspace poison -> must never be dereferenced raw).
__device__ __forceinline__ void gather8h(int ne, const int* __restrict__ er,
                                         const uint4* __restrict__ g16, int sub, int N,
                                         __half2& a0, __half2& a1, __half2& a2) {
#pragma unroll
    for (int r = 0; r < SLOTS / 32; ++r) {
        int base = r * 32 + sub * 4;
        if (base < ne) {
            int4 q = *(const int4*)(er + base);
            int i1 = (base + 1 < ne) ? q.y : N;
            int i2 = (base + 2 < ne) ? q.z : N;
            int i3 = (base + 3 < ne) ? q.w : N;
            uint4 v0 = g16[q.x];
            uint4 v1 = g16[i1];
            uint4 v2 = g16[i2];
            uint4 v3 = g16[i3];
            addh2(a0, a1, a2, v0);
            addh2(a0, a1, a2, v1);
            addh2(a0, a1, a2, v2);
            addh2(a0, a1, a2, v3);
        }
    }
}

// ---------------- fused: gather + epilogue (+ next matmul), 8 lanes per node ----------------
// PREP=0: gout = dinv * (relu(dinv*(sum+self)+b) @ W)
// PREP=1: gout = dinv *  relu(dinv*(sum+self)+b)
template<int PREP>
__global__ __launch_bounds__(256) void gcn_layer8_kernel(
        const int* __restrict__ cnt, const int* __restrict__ ell,
        const int* __restrict__ ovf_meta, const int* __restrict__ ovf_dst,
        const int* __restrict__ ovf_src, const float* __restrict__ dinv,
        const uint4* __restrict__ gin, uint4* __restrict__ gout,
        const float* __restrict__ W, const float* __restrict__ b, int N) {
    int t = blockIdx.x * 256 + threadIdx.x;
    int i = t >> 3;
    int sub = t & 7;
    if (t == 0) gout[N] = make_uint4(0u, 0u, 0u, 0u);   // keep zero row alive
    if (i >= N) return;
    int n = cnt[i];
    int ne = n < SLOTS ? n : SLOTS;
    const int* er = ell + (size_t)i * SLOTS;
    __half2 a0 = __float2half2_rn(0.f), a1 = a0, a2 = a0;
    gather8h(ne, er, gin, sub, N, a0, a1, a2);
    // self-loop term, added exactly once across the subgroup
    if (sub == 0) addh2(a0, a1, a2, gin[i]);
    if (n > SLOTS && sub == 2) {  // ~never taken; correct fallback for deg>SLOTS
        int m = ovf_meta[0];
        m = m < OVFCAP ? m : OVFCAP;
        for (int tt = 0; tt < m; ++tt) {
            if (ovf_dst[tt] == i) addh2(a0, a1, a2, gin[ovf_src[tt]]);
        }
    }
    // packed butterfly (all 8 lanes end with the total)
#pragma unroll
    for (int m = 1; m < 8; m <<= 1) {
        a0 = __hadd2(a0, shfl_xor_h2(a0, m));
        a1 = __hadd2(a1, shfl_xor_h2(a1, m));
        a2 = __hadd2(a2, shfl_xor_h2(a2, m));
    }
    if (sub != 0) return;
    float2 f0 = __half22float2(a0), f1 = __half22float2(a1), f2 = __half22float2(a2);
    float acc[HID] = { f0.x, f0.y, f1.x, f1.y, f2.x, f2.y };
    float dv = dinv[i];
    float h[HID];
#pragma unroll
    for (int f = 0; f < HID; ++f) {
        float u = dv * acc[f] + b[f];
        h[f] = u > 0.0f ? u : 0.0f;
    }
    float o[HID];
    if (PREP) {
#pragma unroll
        for (int f = 0; f < HID; ++f) o[f] = dv * h[f];
    } else {
#pragma unroll
        for (int fo = 0; fo < HID; ++fo) {
            float s = 0.0f;
#pragma unroll
            for (int fi = 0; fi < HID; ++fi) s += h[fi] * W[fi * HID + fo];
            o[fo] = dv * s;
        }
    }
    gout[i] = packh(o);
}

// ---------------- pool: gather conv7 + Wf + relu + LDS mean-pool, 8 lanes per node ----------------
__global__ __launch_bounds__(256) void pool_kernel(
        const int* __restrict__ cnt, const int* __restrict__ ell,
        const int* __restrict__ ovf_meta, const int* __restrict__ ovf_dst,
        const int* __restrict__ ovf_src, const float* __restrict__ dinv,
        const uint4* __restrict__ gin, const int* __restrict__ batch,
        const float* __restrict__ Wf, const float* __restrict__ bf,
        float* __restrict__ pooled, float* __restrict__ gcnt, int N) {
    __shared__ float sp[NG * NC];
    __shared__ float sc[NG];
    __shared__ int srange[2];
    for (int k = threadIdx.x; k < NG * NC; k += 256) sp[k] = 0.0f;
    if (threadIdx.x < NG) sc[threadIdx.x] = 0.0f;
    int start = blockIdx.x * 32;           // 32 nodes per block (256 thr / 8)
    int endi = min(start + 32, N) - 1;
    if (threadIdx.x == 0) {
        srange[0] = batch[start];   // batch is sorted
        srange[1] = batch[endi];
    }
    __syncthreads();
    int t = blockIdx.x * 256 + threadIdx.x;
    int i = t >> 3;
    int sub = t & 7;
    if (i < N) {
        int n = cnt[i];
        int ne = n < SLOTS ? n : SLOTS;
        const int* er = ell + (size_t)i * SLOTS;
        __half2 a0 = __float2half2_rn(0.f), a1 = a0, a2 = a0;
        gather8h(ne, er, gin, sub, N, a0, a1, a2);
        if (sub == 0) addh2(a0, a1, a2, gin[i]);
        if (n > SLOTS && sub == 2) {
            int m = ovf_meta[0];
            m = m < OVFCAP ? m : OVFCAP;
            for (int tt = 0; tt < m; ++tt) {
                if (ovf_dst[tt] == i) addh2(a0, a1, a2, gin[ovf_src[tt]]);
            }
        }
#pragma unroll
        for (int m = 1; m < 8; m <<= 1) {
            a0 = __hadd2(a0, shfl_xor_h2(a0, m));
            a1 = __hadd2(a1, shfl_xor_h2(a1, m));
            a2 = __hadd2(a2, shfl_xor_h2(a2, m));
        }
        if (sub == 0) {
            float2 f0 = __half22float2(a0), f1 = __half22float2(a1), f2 = __half22float2(a2);
            float acc[HID] = { f0.x, f0.y, f1.x, f1.y, f2.x, f2.y };
            float dv = dinv[i];
            float u[HID];
#pragma unroll
            for (int f = 0; f < HID; ++f) u[f] = dv * acc[f];
            int bg = batch[i];
#pragma unroll
            for (int c = 0; c < NC; ++c) {
                float v = bf[c];
#pragma unroll
                for (int f = 0; f < HID; ++f) v += u[f] * Wf[f * NC + c];
                v = v > 0.0f ? v : 0.0f;
                atomicAdd(&sp[bg * NC + c], v);
            }
            atomicAdd(&sc[bg], 1.0f);
        }
    }
    __syncthreads();
    int bmin = srange[0], bmax = srange[1];
    int rows = bmax - bmin + 1;
    for (int k = threadIdx.x; k < rows * NC; k += 256) {
        int r = bmin + k / NC, c = k % NC;
        float v = sp[r * NC + c];
        if (v != 0.0f) atomicAdd(&pooled[r * NC + c], v);
    }
    for (int k = threadIdx.x; k < rows; k += 256) {
        float v = sc[bmin + k];
        if (v != 0.0f) atomicAdd(&gcnt[bmin + k], v);
    }
}

// ---------------- mean + log_softmax ----------------
__global__ void logsm_kernel(const float* __restrict__ pooled, const float* __restrict__ gcnt,
                             float* __restrict__ out) {
    int gidx = threadIdx.x;
    if (gidx >= NG) return;
    float c = gcnt[gidx];
    c = c > 1.0f ? c : 1.0f;
    float v[NC];
    float m = -1e30f;
#pragma unroll
    for (int k = 0; k < NC; ++k) {
        v[k] = pooled[gidx * NC + k] / c;
        m = v[k] > m ? v[k] : m;
    }
    float s = 0.0f;
#pragma unroll
    for (int k = 0; k < NC; ++k) s += expf(v[k] - m);
    float ls = logf(s);
#pragma unroll
    for (int k = 0; k < NC; ++k) out[gidx * NC + k] = v[k] - m - ls;
}

extern "C" void kernel_launch(void* const* d_in, const int* in_sizes, int n_in,
                              void* d_out, int out_size, void* d_ws, size_t ws_size,
                              hipStream_t stream) {
    const float* x     = (const float*)d_in[0];
    const int*   ei    = (const int*)d_in[1];
    const int*   batch = (const int*)d_in[2];
    const float* W[7];
    const float* b[7];
    for (int l = 0; l < 7; ++l) {
        W[l] = (const float*)d_in[3 + 2 * l];
        b[l] = (const float*)d_in[4 + 2 * l];
    }
    const int N = in_sizes[2];
    const int E = in_sizes[1] / 2;
    const int* src = ei;
    const int* dst = ei + E;
    float* out = (float*)d_out;

    // workspace layout (16B-aligned blocks); cnt first, ovf_meta adjacent -> ONE memset
    char* wp = (char*)d_ws;
    int* cnt       = (int*)wp;      wp += (((size_t)N * 4 + 15) & ~15ull);
    int* ovf_meta  = (int*)wp;      wp += 16;
    int* ovf_dst   = (int*)wp;      wp += OVFCAP * 4;
    int* ovf_src   = (int*)wp;      wp += OVFCAP * 4;
    float* dinv    = (float*)wp;    wp += (((size_t)N * 4 + 15) & ~15ull);
    uint4* g_a     = (uint4*)wp;    wp += (size_t)(N + 1) * 16;   // +1: zero row for pads
    uint4* g_b     = (uint4*)wp;    wp += (size_t)(N + 1) * 16;
    float* pooled  = (float*)wp;    wp += NG * NC * 4;
    float* gcnt    = (float*)wp;    wp += (((size_t)NG * 4 + 15) & ~15ull);
    int* ell       = (int*)wp;      wp += (size_t)N * SLOTS * 4;

    hipMemsetAsync(cnt, 0, (((size_t)N * 4 + 15) & ~15ull) + 16, stream);  // cnt + ovf_meta
    hipMemsetAsync(pooled, 0, (NG * NC + NG) * sizeof(float), stream);

    const int BT = 256;
    int bn8 = ((size_t)N * 8 + BT - 1) / BT;
    int bes = ((E >> 2) + BT - 1) / BT;
    if (bes < 1) bes = 1;

    edge_scatter_kernel<<<bes, BT, 0, stream>>>(src, dst, E, cnt, ell,
                                                ovf_meta, ovf_dst, ovf_src);

    layer1_kernel<<<bn8, BT, 0, stream>>>(x, W[0], cnt, dinv, g_a, N);

    // 5 mid layers: (b1,W2) .. (b5,W6), alternating g buffers
    gcn_layer8_kernel<0><<<bn8, BT, 0, stream>>>(cnt, ell, ovf_meta, ovf_dst, ovf_src, dinv, g_a, g_b, W[1], b[0], N);
    gcn_layer8_kernel<0><<<bn8, BT, 0, stream>>>(cnt, ell, ovf_meta, ovf_dst, ovf_src, dinv, g_b, g_a, W[2], b[1], N);
    gcn_layer8_kernel<0><<<bn8, BT, 0, stream>>>(cnt, ell, ovf_meta, ovf_dst, ovf_src, dinv, g_a, g_b, W[3], b[2], N);
    gcn_layer8_kernel<0><<<bn8, BT, 0, stream>>>(cnt, ell, ovf_meta, ovf_dst, ovf_src, dinv, g_b, g_a, W[4], b[3], N);
    gcn_layer8_kernel<0><<<bn8, BT, 0, stream>>>(cnt, ell, ovf_meta, ovf_dst, ovf_src, dinv, g_a, g_b, W[5], b[4], N);
    // layer 6 epilogue (b6), no next W
    gcn_layer8_kernel<1><<<bn8, BT, 0, stream>>>(cnt, ell, ovf_meta, ovf_dst, ovf_src, dinv, g_b, g_a, nullptr, b[5], N);
    // conv7 gather + Wf + bf + relu + pool
    pool_kernel<<<bn8, BT, 0, stream>>>(cnt, ell, ovf_meta, ovf_dst, ovf_src, dinv, g_a, batch, W[6], b[6], pooled, gcnt, N);
    logsm_kernel<<<1, 64, 0, stream>>>(pooled, gcnt, out);
}

// Round 8
// 321.048 us; speedup vs baseline: 1.7217x; 1.7217x over previous
//
#include <hip/hip_runtime.h>
#include <hip/hip_bf16.h>
#include <hip/hip_fp16.h>
#include <math.h>

#define NF     128
#define HID    6
#define NC     10
#define NG     64
#define SLOTS  64     // ELL row capacity (deg ~ Poisson(32); P(deg>64) ~ 4e-7/node)
#define OVFCAP 8192

// bucket build params
#define BKT_SH    7
#define BKT_NODES 128
#define NBK_MAX   1024     // supports N <= 131072
#define EPB       4096     // edges per phase-1 block (256 thr x 16)
#define BCAP      5120     // per-bucket capacity (mean 4096, +16 sigma)
#define BOVFCAP   4096

// v7 = v4 (verified best: 327.9us, bucket_scatter 40us) + consolidation trims.
// Bracketing evidence r2/r6: direct global scatter (either into bucket_arr or ell)
// costs 100-190MB writes and loses 2-8x; the LDS-staged two-phase build stays.
// Trims: dinv array deleted (rsqrtf(cnt+1) recomputed per consumer, bit-identical),
// int4 sentinel init in ell_build, single init kernel replaces 2 memsets.

// g row: 6 values as fp16, padded to 16B (8 halves) -> ONE dwordx4 per neighbor.
__device__ __forceinline__ void addh2(__half2& a0, __half2& a1, __half2& a2, uint4 q) {
    const __half2* h = (const __half2*)&q;
    a0 = __hadd2(a0, h[0]);
    a1 = __hadd2(a1, h[1]);
    a2 = __hadd2(a2, h[2]);
}

__device__ __forceinline__ __half2 shfl_xor_h2(__half2 v, int m) {
    union { __half2 h; unsigned int u; } a;
    a.h = v;
    a.u = __shfl_xor(a.u, m);
    return a.h;
}

__device__ __forceinline__ uint4 packh(const float* v) {
    uint4 q;
    __half2* h = (__half2*)&q;
    h[0] = __floats2half2_rn(v[0], v[1]);
    h[1] = __floats2half2_rn(v[2], v[3]);
    h[2] = __floats2half2_rn(v[4], v[5]);
    h[3] = __floats2half2_rn(0.f, 0.f);
    return q;
}

// ---------------- init: zero cursor+metas and pooled+gcnt in one dispatch ----------------
__global__ __launch_bounds__(256) void init_kernel(int* __restrict__ bucket_cursor,
                                                   float* __restrict__ pooled) {
    int t = blockIdx.x * 256 + threadIdx.x;
    if (t < NBK_MAX + 8) bucket_cursor[t] = 0;            // cursor + ovf_meta + bovf_meta
    int p = t - (NBK_MAX + 8);
    if (p >= 0 && p < NG * NC + NG) pooled[p] = 0.0f;     // pooled + gcnt (contiguous)
}

// ---------------- phase 1: bin edges by dst>>7, rank-from-count, staged coalesced copy-out ----------------
// v4: stage the FINAL global index alongside the payload (binary search deleted).
__global__ __launch_bounds__(256) void bucket_scatter_kernel(
        const int* __restrict__ src, const int* __restrict__ dst, int E, int nbk,
        int* __restrict__ bucket_cursor, unsigned int* __restrict__ bucket_arr,
        int* __restrict__ bovf_meta, int2* __restrict__ bovf) {
    __shared__ int cntL[NBK_MAX];
    __shared__ int offs[NBK_MAX];
    __shared__ int gb[NBK_MAX];
    __shared__ int wtot[4];
    __shared__ unsigned int stage[EPB];
    __shared__ unsigned int stage_gi[EPB];
    int tid = threadIdx.x;
    for (int k = tid; k < NBK_MAX; k += 256) cntL[k] = 0;
    __syncthreads();                                     // B1
    int e0 = blockIdx.x * EPB;
    int cnt_e = E - e0; if (cnt_e > EPB) cnt_e = EPB;
    int sreg[16], dreg[16], rank[16];
    // pass A: load edges + LDS-atomic rank (atomic return IS the local rank)
    if (cnt_e == EPB && (E & 3) == 0) {
        const int4* s4p = (const int4*)(src + e0);
        const int4* d4p = (const int4*)(dst + e0);
#pragma unroll
        for (int k = 0; k < 4; ++k) {
            int4 sv = s4p[k * 256 + tid];
            int4 dv = d4p[k * 256 + tid];
            sreg[4*k+0] = sv.x; sreg[4*k+1] = sv.y; sreg[4*k+2] = sv.z; sreg[4*k+3] = sv.w;
            dreg[4*k+0] = dv.x; dreg[4*k+1] = dv.y; dreg[4*k+2] = dv.z; dreg[4*k+3] = dv.w;
        }
#pragma unroll
        for (int k = 0; k < 16; ++k) rank[k] = atomicAdd(&cntL[dreg[k] >> BKT_SH], 1);
    } else {
#pragma unroll
        for (int k = 0; k < 16; ++k) {
            int e = e0 + k * 256 + tid;
            if (e < E) {
                dreg[k] = dst[e]; sreg[k] = src[e];
                rank[k] = atomicAdd(&cntL[dreg[k] >> BKT_SH], 1);
            } else dreg[k] = -1;
        }
    }
    __syncthreads();                                     // B2
    // exclusive scan over 1024 bucket counts: 4/thread + wave shfl-scan + wave-total combine
    int base = tid * 4;
    int c0 = cntL[base], c1 = cntL[base + 1], c2 = cntL[base + 2], c3 = cntL[base + 3];
    int tsum = c0 + c1 + c2 + c3;
    int lane = tid & 63, wv = tid >> 6;
    int v = tsum;
#pragma unroll
    for (int off = 1; off < 64; off <<= 1) {
        int u = __shfl_up(v, off);
        if (lane >= off) v += u;
    }
    if (lane == 63) wtot[wv] = v;
    __syncthreads();                                     // B3
    int wbase = 0;
    for (int w = 0; w < wv; ++w) wbase += wtot[w];
    int ex = wbase + v - tsum;
    offs[base]     = ex;
    offs[base + 1] = ex + c0;
    offs[base + 2] = ex + c0 + c1;
    offs[base + 3] = ex + c0 + c1 + c2;
    // reserve global spans (one atomic per non-empty bucket per block)
    for (int bb = tid; bb < nbk; bb += 256) {
        int c = cntL[bb];
        if (c > 0) gb[bb] = atomicAdd(&bucket_cursor[bb], c);
    }
    __syncthreads();                                     // B4
    // pass B: stage payload AND final global index (no binary search needed later)
#pragma unroll
    for (int k = 0; k < 16; ++k) {
        int d = dreg[k];
        if (d < 0) continue;
        int b = d >> BKT_SH;
        int pos = offs[b] + rank[k];
        unsigned int p = (unsigned int)(d & (BKT_NODES - 1)) | ((unsigned int)sreg[k] << BKT_SH);
        int grel = gb[b] + rank[k];
        stage[pos] = p;
        if (grel < BCAP) {
            stage_gi[pos] = (unsigned int)b * BCAP + (unsigned int)grel;
        } else {  // bucket capacity overflow (~never)
            stage_gi[pos] = 0xFFFFFFFFu;
            int p2 = atomicAdd(bovf_meta, 1);
            if (p2 < BOVFCAP) bovf[p2] = make_int2(d, sreg[k]);
        }
    }
    __syncthreads();                                     // B5
    // copy out: consecutive j within a bucket run -> consecutive gi -> coalesced writes
    for (int j = tid; j < cnt_e; j += 256) {
        unsigned int gi = stage_gi[j];
        if (gi != 0xFFFFFFFFu) bucket_arr[gi] = stage[j];
    }
}

// ---------------- phase 2: per-bucket ELL build in LDS, pruned coalesced dump ----------------
// ELL rows are padded (within the last occupied int4 chunk) with sentinel index N,
// which points at a zero row of g -> gathers add 4 unconditionally.
__global__ __launch_bounds__(256) void ell_build_kernel(
        const unsigned int* __restrict__ bucket_arr, const int* __restrict__ bucket_cursor,
        const int* __restrict__ bovf_meta, const int2* __restrict__ bovf,
        int* __restrict__ ell, int* __restrict__ cnt,
        int* __restrict__ ovf_meta, int* __restrict__ ovf_dst, int* __restrict__ ovf_src,
        int N) {
    __shared__ int ell_s[BKT_NODES * SLOTS];   // 32KB
    __shared__ int cur[BKT_NODES];
    int b = blockIdx.x;
    int tid = threadIdx.x;
    if (tid < BKT_NODES) cur[tid] = 0;
    {   // int4 sentinel init (8 x ds_write_b128 per thread instead of 32 x b32)
        int4* e4 = (int4*)ell_s;
        int4 sv = make_int4(N, N, N, N);
        for (int k = tid; k < BKT_NODES * SLOTS / 4; k += 256) e4[k] = sv;
    }
    __syncthreads();
    int bc = bucket_cursor[b];
    if (bc > BCAP) bc = BCAP;
    const unsigned int* ba = bucket_arr + (size_t)b * BCAP;
    // uint4-vectorized read (4x fewer loads feeding the LDS-atomic chain); slot order within
    // a row is already nondeterministic (atomic), so reordering is semantics-preserving.
    int bc4 = bc >> 2;
    const uint4* ba4 = (const uint4*)ba;
    for (int j = tid; j < bc4; j += 256) {
        uint4 pv = ba4[j];
        unsigned int ps[4] = { pv.x, pv.y, pv.z, pv.w };
#pragma unroll
        for (int q = 0; q < 4; ++q) {
            unsigned int p = ps[q];
            int r = (int)(p & (BKT_NODES - 1));
            int s = (int)(p >> BKT_SH);
            int slot = atomicAdd(&cur[r], 1);
            if (slot < SLOTS) {
                ell_s[r * SLOTS + slot] = s;
            } else {  // node degree overflow (~never)
                int d = (b << BKT_SH) + r;
                int qq = atomicAdd(ovf_meta, 1);
                if (qq < OVFCAP) { ovf_dst[qq] = d; ovf_src[qq] = s; }
            }
        }
    }
    for (int j = (bc4 << 2) + tid; j < bc; j += 256) {
        unsigned int p = ba[j];
        int r = (int)(p & (BKT_NODES - 1));
        int s = (int)(p >> BKT_SH);
        int slot = atomicAdd(&cur[r], 1);
        if (slot < SLOTS) {
            ell_s[r * SLOTS + slot] = s;
        } else {
            int d = (b << BKT_SH) + r;
            int q = atomicAdd(ovf_meta, 1);
            if (q < OVFCAP) { ovf_dst[q] = d; ovf_src[q] = s; }
        }
    }
    // fold in bucket-capacity overflow edges (list is ~always empty)
    int m = *bovf_meta;
    if (m > BOVFCAP) m = BOVFCAP;
    for (int t = tid; t < m; t += 256) {
        int2 e = bovf[t];
        if ((e.x >> BKT_SH) == b) {
            int r = e.x & (BKT_NODES - 1);
            int slot = atomicAdd(&cur[r], 1);
            if (slot < SLOTS) {
                ell_s[r * SLOTS + slot] = e.y;
            } else {
                int q = atomicAdd(ovf_meta, 1);
                if (q < OVFCAP) { ovf_dst[q] = e.x; ovf_src[q] = e.y; }
            }
        }
    }
    __syncthreads();
    int nid0 = b << BKT_SH;
    int rows = N - nid0; if (rows > BKT_NODES) rows = BKT_NODES;
    if (rows <= 0) return;
    int4* eg = (int4*)(ell + (size_t)nid0 * SLOTS);
    const int4* es = (const int4*)ell_s;
    // dump only occupied int4 chunks (gathers never read past ceil(cnt/4) chunks)
    for (int k = tid; k < rows * (SLOTS / 4); k += 256) {
        int r = k >> 4;            // SLOTS/4 == 16 chunks per row
        int q = k & 15;
        int c = cur[r]; if (c > SLOTS) c = SLOTS;
        if (q * 4 < c) eg[k] = es[k];
    }
    for (int r = tid; r < rows; r += 256) {
        cnt[nid0 + r] = cur[r];
    }
}

// ---------------- layer 1: g = dinv * (x @ W1), 8 lanes per node, fp16 row out ----------------
__global__ __launch_bounds__(256) void layer1_kernel(const float* __restrict__ x,
                                                     const float* __restrict__ W,
                                                     const int* __restrict__ cnt,
                                                     uint4* __restrict__ g16, int N) {
    __shared__ float sW[8 * 100];
    for (int idx = threadIdx.x; idx < NF * HID; idx += 256) {
        int s = idx / 96, r = idx % 96;
        int o = r / 16, j = r % 16;
        sW[s * 100 + o * 16 + j] = W[(s * 16 + j) * HID + o];
    }
    __syncthreads();
    int t = blockIdx.x * 256 + threadIdx.x;
    int i = t >> 3;
    int sub = t & 7;
    if (t == 0) g16[N] = make_uint4(0u, 0u, 0u, 0u);    // zero row for sentinel pads
    if (i >= N) return;
    const float4* xr = (const float4*)(x + (size_t)i * NF + sub * 16);
    float4 xv0 = xr[0], xv1 = xr[1], xv2 = xr[2], xv3 = xr[3];
    const float4* wr = (const float4*)(sW + sub * 100);
    float p[HID];
#pragma unroll
    for (int o = 0; o < HID; ++o) {
        float4 w0 = wr[o * 4 + 0], w1 = wr[o * 4 + 1], w2 = wr[o * 4 + 2], w3 = wr[o * 4 + 3];
        p[o] = xv0.x * w0.x + xv0.y * w0.y + xv0.z * w0.z + xv0.w * w0.w
             + xv1.x * w1.x + xv1.y * w1.y + xv1.z * w1.z + xv1.w * w1.w
             + xv2.x * w2.x + xv2.y * w2.y + xv2.z * w2.z + xv2.w * w2.w
             + xv3.x * w3.x + xv3.y * w3.y + xv3.z * w3.z + xv3.w * w3.w;
    }
#pragma unroll
    for (int m = 1; m < 8; m <<= 1) {
#pragma unroll
        for (int o = 0; o < HID; ++o) p[o] += __shfl_xor(p[o], m);
    }
    if (sub == 0) {
        float dv = rsqrtf((float)cnt[i] + 1.0f);   // +1 self loop (dinv array deleted)
        float v[HID];
#pragma unroll
        for (int o = 0; o < HID; ++o) v[o] = dv * p[o];
        g16[i] = packh(v);
    }
}

// ---------------- chunked ELL gather (fp16 rows, fp16 accumulate, padded rows) ----------------
// sub-lane owns chunk [4*sub,4*sub+4) then [32+4*sub,...). All 4 entries added
// unconditionally; pads hit the zero row at index N.
__device__ __forceinline__ void gather8h(int ne, const int* __restrict__ er,
                                         const uint4* __restrict__ g16, int sub,
                                         __half2& a0, __half2& a1, __half2& a2) {
#pragma unroll
    for (int r = 0; r < SLOTS / 32; ++r) {
        int base = r * 32 + sub * 4;
        if (base < ne) {
            int4 q = *(const int4*)(er + base);
            uint4 v0 = g16[q.x];
            uint4 v1 = g16[q.y];
            uint4 v2 = g16[q.z];
            uint4 v3 = g16[q.w];
            addh2(a0, a1, a2, v0);
            addh2(a0, a1, a2, v1);
            addh2(a0, a1, a2, v2);
            addh2(a0, a1, a2, v3);
        }
    }
}

// ---------------- fused: gather + epilogue (+ next matmul), 8 lanes per node ----------------
// PREP=0: gout = dinv * (relu(dinv*(sum+self)+b) @ W)
// PREP=1: gout = dinv *  relu(dinv*(sum+self)+b)
template<int PREP>
__global__ __launch_bounds__(256) void gcn_layer8_kernel(
        const int* __restrict__ cnt, const int* __restrict__ ell,
        const int* __restrict__ ovf_meta, const int* __restrict__ ovf_dst,
        const int* __restrict__ ovf_src,
        const uint4* __restrict__ gin, uint4* __restrict__ gout,
        const float* __restrict__ W, const float* __restrict__ b, int N) {
    int t = blockIdx.x * 256 + threadIdx.x;
    int i = t >> 3;
    int sub = t & 7;
    if (t == 0) gout[N] = make_uint4(0u, 0u, 0u, 0u);   // keep zero row alive
    if (i >= N) return;
    int n = cnt[i];
    int ne = n < SLOTS ? n : SLOTS;
    const int* er = ell + (size_t)i * SLOTS;
    __half2 a0 = __float2half2_rn(0.f), a1 = a0, a2 = a0;
    gather8h(ne, er, gin, sub, a0, a1, a2);
    // self-loop term, added exactly once across the subgroup
    if (sub == 0) addh2(a0, a1, a2, gin[i]);
    if (n > SLOTS && sub == 2) {  // ~never taken; correct fallback for deg>SLOTS
        int m = ovf_meta[0];
        m = m < OVFCAP ? m : OVFCAP;
        for (int tt = 0; tt < m; ++tt) {
            if (ovf_dst[tt] == i) addh2(a0, a1, a2, gin[ovf_src[tt]]);
        }
    }
    // packed butterfly (all 8 lanes end with the total)
#pragma unroll
    for (int m = 1; m < 8; m <<= 1) {
        a0 = __hadd2(a0, shfl_xor_h2(a0, m));
        a1 = __hadd2(a1, shfl_xor_h2(a1, m));
        a2 = __hadd2(a2, shfl_xor_h2(a2, m));
    }
    if (sub != 0) return;
    float2 f0 = __half22float2(a0), f1 = __half22float2(a1), f2 = __half22float2(a2);
    float acc[HID] = { f0.x, f0.y, f1.x, f1.y, f2.x, f2.y };
    float dv = rsqrtf((float)n + 1.0f);   // dinv recomputed (bit-identical across kernels)
    float h[HID];
#pragma unroll
    for (int f = 0; f < HID; ++f) {
        float u = dv * acc[f] + b[f];
        h[f] = u > 0.0f ? u : 0.0f;
    }
    float o[HID];
    if (PREP) {
#pragma unroll
        for (int f = 0; f < HID; ++f) o[f] = dv * h[f];
    } else {
#pragma unroll
        for (int fo = 0; fo < HID; ++fo) {
            float s = 0.0f;
#pragma unroll
            for (int fi = 0; fi < HID; ++fi) s += h[fi] * W[fi * HID + fo];
            o[fo] = dv * s;
        }
    }
    gout[i] = packh(o);
}

// ---------------- pool: gather conv7 + Wf + relu + LDS mean-pool, 8 lanes per node ----------------
__global__ __launch_bounds__(256) void pool_kernel(
        const int* __restrict__ cnt, const int* __restrict__ ell,
        const int* __restrict__ ovf_meta, const int* __restrict__ ovf_dst,
        const int* __restrict__ ovf_src,
        const uint4* __restrict__ gin, const int* __restrict__ batch,
        const float* __restrict__ Wf, const float* __restrict__ bf,
        float* __restrict__ pooled, float* __restrict__ gcnt, int N) {
    __shared__ float sp[NG * NC];
    __shared__ float sc[NG];
    __shared__ int srange[2];
    for (int k = threadIdx.x; k < NG * NC; k += 256) sp[k] = 0.0f;
    if (threadIdx.x < NG) sc[threadIdx.x] = 0.0f;
    int start = blockIdx.x * 32;           // 32 nodes per block (256 thr / 8)
    int endi = min(start + 32, N) - 1;
    if (threadIdx.x == 0) {
        srange[0] = batch[start];   // batch is sorted
        srange[1] = batch[endi];
    }
    __syncthreads();
    int t = blockIdx.x * 256 + threadIdx.x;
    int i = t >> 3;
    int sub = t & 7;
    if (i < N) {
        int n = cnt[i];
        int ne = n < SLOTS ? n : SLOTS;
        const int* er = ell + (size_t)i * SLOTS;
        __half2 a0 = __float2half2_rn(0.f), a1 = a0, a2 = a0;
        gather8h(ne, er, gin, sub, a0, a1, a2);
        if (sub == 0) addh2(a0, a1, a2, gin[i]);
        if (n > SLOTS && sub == 2) {
            int m = ovf_meta[0];
            m = m < OVFCAP ? m : OVFCAP;
            for (int tt = 0; tt < m; ++tt) {
                if (ovf_dst[tt] == i) addh2(a0, a1, a2, gin[ovf_src[tt]]);
            }
        }
#pragma unroll
        for (int m = 1; m < 8; m <<= 1) {
            a0 = __hadd2(a0, shfl_xor_h2(a0, m));
            a1 = __hadd2(a1, shfl_xor_h2(a1, m));
            a2 = __hadd2(a2, shfl_xor_h2(a2, m));
        }
        if (sub == 0) {
            float2 f0 = __half22float2(a0), f1 = __half22float2(a1), f2 = __half22float2(a2);
            float acc[HID] = { f0.x, f0.y, f1.x, f1.y, f2.x, f2.y };
            float dv = rsqrtf((float)n + 1.0f);
            float u[HID];
#pragma unroll
            for (int f = 0; f < HID; ++f) u[f] = dv * acc[f];
            int bg = batch[i];
#pragma unroll
            for (int c = 0; c < NC; ++c) {
                float v = bf[c];
#pragma unroll
                for (int f = 0; f < HID; ++f) v += u[f] * Wf[f * NC + c];
                v = v > 0.0f ? v : 0.0f;
                atomicAdd(&sp[bg * NC + c], v);
            }
            atomicAdd(&sc[bg], 1.0f);
        }
    }
    __syncthreads();
    int bmin = srange[0], bmax = srange[1];
    int rows = bmax - bmin + 1;
    for (int k = threadIdx.x; k < rows * NC; k += 256) {
        int r = bmin + k / NC, c = k % NC;
        float v = sp[r * NC + c];
        if (v != 0.0f) atomicAdd(&pooled[r * NC + c], v);
    }
    for (int k = threadIdx.x; k < rows; k += 256) {
        float v = sc[bmin + k];
        if (v != 0.0f) atomicAdd(&gcnt[bmin + k], v);
    }
}

// ---------------- mean + log_softmax ----------------
__global__ void logsm_kernel(const float* __restrict__ pooled, const float* __restrict__ gcnt,
                             float* __restrict__ out) {
    int gidx = threadIdx.x;
    if (gidx >= NG) return;
    float c = gcnt[gidx];
    c = c > 1.0f ? c : 1.0f;
    float v[NC];
    float m = -1e30f;
#pragma unroll
    for (int k = 0; k < NC; ++k) {
        v[k] = pooled[gidx * NC + k] / c;
        m = v[k] > m ? v[k] : m;
    }
    float s = 0.0f;
#pragma unroll
    for (int k = 0; k < NC; ++k) s += expf(v[k] - m);
    float ls = logf(s);
#pragma unroll
    for (int k = 0; k < NC; ++k) out[gidx * NC + k] = v[k] - m - ls;
}

extern "C" void kernel_launch(void* const* d_in, const int* in_sizes, int n_in,
                              void* d_out, int out_size, void* d_ws, size_t ws_size,
                              hipStream_t stream) {
    const float* x     = (const float*)d_in[0];
    const int*   ei    = (const int*)d_in[1];
    const int*   batch = (const int*)d_in[2];
    const float* W[7];
    const float* b[7];
    for (int l = 0; l < 7; ++l) {
        W[l] = (const float*)d_in[3 + 2 * l];
        b[l] = (const float*)d_in[4 + 2 * l];
    }
    const int N = in_sizes[2];
    const int E = in_sizes[1] / 2;
    const int nbk = (N + BKT_NODES - 1) >> BKT_SH;
    const int* src = ei;
    const int* dst = ei + E;
    float* out = (float*)d_out;

    // workspace layout (16B-aligned blocks)
    char* wp = (char*)d_ws;
    int* bucket_cursor = (int*)wp;  wp += (size_t)NBK_MAX * 4;
    int* ovf_meta  = (int*)wp;      wp += 16;
    int* bovf_meta = (int*)wp;      wp += 16;   // metas contiguous with cursor -> one init span
    int* ovf_dst   = (int*)wp;      wp += OVFCAP * 4;
    int* ovf_src   = (int*)wp;      wp += OVFCAP * 4;
    int2* bovf     = (int2*)wp;     wp += (size_t)BOVFCAP * 8;
    int* cnt       = (int*)wp;      wp += (((size_t)N * 4 + 15) & ~15ull);
    uint4* g_a     = (uint4*)wp;    wp += (size_t)(N + 1) * 16;   // +1: zero row for pads
    uint4* g_b     = (uint4*)wp;    wp += (size_t)(N + 1) * 16;
    float* pooled  = (float*)wp;    wp += NG * NC * 4;            // gcnt follows contiguously
    float* gcnt    = (float*)wp;    wp += (((size_t)NG * 4 + 15) & ~15ull);
    int* ell       = (int*)wp;      wp += (size_t)N * SLOTS * 4;
    unsigned int* bucket_arr = (unsigned int*)wp;  wp += (size_t)nbk * BCAP * 4;

    const int BT = 256;
    int bn8 = ((size_t)N * 8 + BT - 1) / BT;
    int bp1 = (E + EPB - 1) / EPB;

    init_kernel<<<(NBK_MAX + 8 + NG * NC + NG + BT - 1) / BT, BT, 0, stream>>>(bucket_cursor, pooled);

    bucket_scatter_kernel<<<bp1, BT, 0, stream>>>(src, dst, E, nbk, bucket_cursor,
                                                  bucket_arr, bovf_meta, bovf);
    ell_build_kernel<<<nbk, BT, 0, stream>>>(bucket_arr, bucket_cursor, bovf_meta, bovf,
                                             ell, cnt, ovf_meta, ovf_dst, ovf_src, N);

    layer1_kernel<<<bn8, BT, 0, stream>>>(x, W[0], cnt, g_a, N);

    // 5 mid layers: (b1,W2) .. (b5,W6), alternating g buffers
    gcn_layer8_kernel<0><<<bn8, BT, 0, stream>>>(cnt, ell, ovf_meta, ovf_dst, ovf_src, g_a, g_b, W[1], b[0], N);
    gcn_layer8_kernel<0><<<bn8, BT, 0, stream>>>(cnt, ell, ovf_meta, ovf_dst, ovf_src, g_b, g_a, W[2], b[1], N);
    gcn_layer8_kernel<0><<<bn8, BT, 0, stream>>>(cnt, ell, ovf_meta, ovf_dst, ovf_src, g_a, g_b, W[3], b[2], N);
    gcn_layer8_kernel<0><<<bn8, BT, 0, stream>>>(cnt, ell, ovf_meta, ovf_dst, ovf_src, g_b, g_a, W[4], b[3], N);
    gcn_layer8_kernel<0><<<bn8, BT, 0, stream>>>(cnt, ell, ovf_meta, ovf_dst, ovf_src, g_a, g_b, W[5], b[4], N);
    // layer 6 epilogue (b6), no next W
    gcn_layer8_kernel<1><<<bn8, BT, 0, stream>>>(cnt, ell, ovf_meta, ovf_dst, ovf_src, g_b, g_a, nullptr, b[5], N);
    // conv7 gather + Wf + bf + relu + pool
    pool_kernel<<<bn8, BT, 0, stream>>>(cnt, ell, ovf_meta, ovf_dst, ovf_src, g_a, batch, W[6], b[6], pooled, gcnt, N);
    logsm_kernel<<<1, 64, 0, stream>>>(pooled, gcnt, out);
}

// Round 9
// 316.516 us; speedup vs baseline: 1.7463x; 1.0143x over previous
//
#include <hip/hip_runtime.h>
#include <hip/hip_bf16.h>
#include <hip/hip_fp16.h>
#include <math.h>

#define NF     128
#define HID    6
#define NC     10
#define NG     64
#define SLOTS  64     // ELL row capacity (deg ~ Poisson(32); P(deg>64) ~ 4e-7/node)
#define OVFCAP 8192

// bucket build params
#define BKT_SH    7
#define BKT_NODES 128
#define NBK_MAX   1024     // supports N <= 131072
#define EPB       4096     // edges per phase-1 block (256 thr x 16)
#define BCAP      5120     // per-bucket capacity (mean 4096, +16 sigma)
#define BOVFCAP   4096

// v8 = v7 (321.0us) + 4-lane gather restructure.
// r8 budget: gather family (6x layer + pool) ~200us of the 275us controllable remainder.
// Old gather: 8 subs/node, per-thread 1 ell + 4 dependent scattered g loads (MLP=5).
// New: 4 subs/node, chunks {sub, sub+4, sub+8, sub+12}: per-thread 2 ell + 8 g loads
// in flight (MLP=10), half the threads, butterfly 3->2 stages.

// g row: 6 values as fp16, padded to 16B (8 halves) -> ONE dwordx4 per neighbor.
__device__ __forceinline__ void addh2(__half2& a0, __half2& a1, __half2& a2, uint4 q) {
    const __half2* h = (const __half2*)&q;
    a0 = __hadd2(a0, h[0]);
    a1 = __hadd2(a1, h[1]);
    a2 = __hadd2(a2, h[2]);
}

__device__ __forceinline__ __half2 shfl_xor_h2(__half2 v, int m) {
    union { __half2 h; unsigned int u; } a;
    a.h = v;
    a.u = __shfl_xor(a.u, m);
    return a.h;
}

__device__ __forceinline__ uint4 packh(const float* v) {
    uint4 q;
    __half2* h = (__half2*)&q;
    h[0] = __floats2half2_rn(v[0], v[1]);
    h[1] = __floats2half2_rn(v[2], v[3]);
    h[2] = __floats2half2_rn(v[4], v[5]);
    h[3] = __floats2half2_rn(0.f, 0.f);
    return q;
}

// ---------------- init: zero cursor+metas and pooled+gcnt in one dispatch ----------------
__global__ __launch_bounds__(256) void init_kernel(int* __restrict__ bucket_cursor,
                                                   float* __restrict__ pooled) {
    int t = blockIdx.x * 256 + threadIdx.x;
    if (t < NBK_MAX + 8) bucket_cursor[t] = 0;            // cursor + ovf_meta + bovf_meta
    int p = t - (NBK_MAX + 8);
    if (p >= 0 && p < NG * NC + NG) pooled[p] = 0.0f;     // pooled + gcnt (contiguous)
}

// ---------------- phase 1: bin edges by dst>>7, rank-from-count, staged coalesced copy-out ----------------
__global__ __launch_bounds__(256) void bucket_scatter_kernel(
        const int* __restrict__ src, const int* __restrict__ dst, int E, int nbk,
        int* __restrict__ bucket_cursor, unsigned int* __restrict__ bucket_arr,
        int* __restrict__ bovf_meta, int2* __restrict__ bovf) {
    __shared__ int cntL[NBK_MAX];
    __shared__ int offs[NBK_MAX];
    __shared__ int gb[NBK_MAX];
    __shared__ int wtot[4];
    __shared__ unsigned int stage[EPB];
    __shared__ unsigned int stage_gi[EPB];
    int tid = threadIdx.x;
    for (int k = tid; k < NBK_MAX; k += 256) cntL[k] = 0;
    __syncthreads();                                     // B1
    int e0 = blockIdx.x * EPB;
    int cnt_e = E - e0; if (cnt_e > EPB) cnt_e = EPB;
    int sreg[16], dreg[16], rank[16];
    // pass A: load edges + LDS-atomic rank (atomic return IS the local rank)
    if (cnt_e == EPB && (E & 3) == 0) {
        const int4* s4p = (const int4*)(src + e0);
        const int4* d4p = (const int4*)(dst + e0);
#pragma unroll
        for (int k = 0; k < 4; ++k) {
            int4 sv = s4p[k * 256 + tid];
            int4 dv = d4p[k * 256 + tid];
            sreg[4*k+0] = sv.x; sreg[4*k+1] = sv.y; sreg[4*k+2] = sv.z; sreg[4*k+3] = sv.w;
            dreg[4*k+0] = dv.x; dreg[4*k+1] = dv.y; dreg[4*k+2] = dv.z; dreg[4*k+3] = dv.w;
        }
#pragma unroll
        for (int k = 0; k < 16; ++k) rank[k] = atomicAdd(&cntL[dreg[k] >> BKT_SH], 1);
    } else {
#pragma unroll
        for (int k = 0; k < 16; ++k) {
            int e = e0 + k * 256 + tid;
            if (e < E) {
                dreg[k] = dst[e]; sreg[k] = src[e];
                rank[k] = atomicAdd(&cntL[dreg[k] >> BKT_SH], 1);
            } else dreg[k] = -1;
        }
    }
    __syncthreads();                                     // B2
    // exclusive scan over 1024 bucket counts: 4/thread + wave shfl-scan + wave-total combine
    int base = tid * 4;
    int c0 = cntL[base], c1 = cntL[base + 1], c2 = cntL[base + 2], c3 = cntL[base + 3];
    int tsum = c0 + c1 + c2 + c3;
    int lane = tid & 63, wv = tid >> 6;
    int v = tsum;
#pragma unroll
    for (int off = 1; off < 64; off <<= 1) {
        int u = __shfl_up(v, off);
        if (lane >= off) v += u;
    }
    if (lane == 63) wtot[wv] = v;
    __syncthreads();                                     // B3
    int wbase = 0;
    for (int w = 0; w < wv; ++w) wbase += wtot[w];
    int ex = wbase + v - tsum;
    offs[base]     = ex;
    offs[base + 1] = ex + c0;
    offs[base + 2] = ex + c0 + c1;
    offs[base + 3] = ex + c0 + c1 + c2;
    // reserve global spans (one atomic per non-empty bucket per block)
    for (int bb = tid; bb < nbk; bb += 256) {
        int c = cntL[bb];
        if (c > 0) gb[bb] = atomicAdd(&bucket_cursor[bb], c);
    }
    __syncthreads();                                     // B4
    // pass B: stage payload AND final global index (no binary search needed later)
#pragma unroll
    for (int k = 0; k < 16; ++k) {
        int d = dreg[k];
        if (d < 0) continue;
        int b = d >> BKT_SH;
        int pos = offs[b] + rank[k];
        unsigned int p = (unsigned int)(d & (BKT_NODES - 1)) | ((unsigned int)sreg[k] << BKT_SH);
        int grel = gb[b] + rank[k];
        stage[pos] = p;
        if (grel < BCAP) {
            stage_gi[pos] = (unsigned int)b * BCAP + (unsigned int)grel;
        } else {  // bucket capacity overflow (~never)
            stage_gi[pos] = 0xFFFFFFFFu;
            int p2 = atomicAdd(bovf_meta, 1);
            if (p2 < BOVFCAP) bovf[p2] = make_int2(d, sreg[k]);
        }
    }
    __syncthreads();                                     // B5
    // copy out: consecutive j within a bucket run -> consecutive gi -> coalesced writes
    for (int j = tid; j < cnt_e; j += 256) {
        unsigned int gi = stage_gi[j];
        if (gi != 0xFFFFFFFFu) bucket_arr[gi] = stage[j];
    }
}

// ---------------- phase 2: per-bucket ELL build in LDS, pruned coalesced dump ----------------
// ELL rows are padded (within the last occupied int4 chunk) with sentinel index N,
// which points at a zero row of g -> gathers add 4 unconditionally.
__global__ __launch_bounds__(256) void ell_build_kernel(
        const unsigned int* __restrict__ bucket_arr, const int* __restrict__ bucket_cursor,
        const int* __restrict__ bovf_meta, const int2* __restrict__ bovf,
        int* __restrict__ ell, int* __restrict__ cnt,
        int* __restrict__ ovf_meta, int* __restrict__ ovf_dst, int* __restrict__ ovf_src,
        int N) {
    __shared__ int ell_s[BKT_NODES * SLOTS];   // 32KB
    __shared__ int cur[BKT_NODES];
    int b = blockIdx.x;
    int tid = threadIdx.x;
    if (tid < BKT_NODES) cur[tid] = 0;
    {   // int4 sentinel init (8 x ds_write_b128 per thread instead of 32 x b32)
        int4* e4 = (int4*)ell_s;
        int4 sv = make_int4(N, N, N, N);
        for (int k = tid; k < BKT_NODES * SLOTS / 4; k += 256) e4[k] = sv;
    }
    __syncthreads();
    int bc = bucket_cursor[b];
    if (bc > BCAP) bc = BCAP;
    const unsigned int* ba = bucket_arr + (size_t)b * BCAP;
    // uint4-vectorized read (4x fewer loads feeding the LDS-atomic chain); slot order within
    // a row is already nondeterministic (atomic), so reordering is semantics-preserving.
    int bc4 = bc >> 2;
    const uint4* ba4 = (const uint4*)ba;
    for (int j = tid; j < bc4; j += 256) {
        uint4 pv = ba4[j];
        unsigned int ps[4] = { pv.x, pv.y, pv.z, pv.w };
#pragma unroll
        for (int q = 0; q < 4; ++q) {
            unsigned int p = ps[q];
            int r = (int)(p & (BKT_NODES - 1));
            int s = (int)(p >> BKT_SH);
            int slot = atomicAdd(&cur[r], 1);
            if (slot < SLOTS) {
                ell_s[r * SLOTS + slot] = s;
            } else {  // node degree overflow (~never)
                int d = (b << BKT_SH) + r;
                int qq = atomicAdd(ovf_meta, 1);
                if (qq < OVFCAP) { ovf_dst[qq] = d; ovf_src[qq] = s; }
            }
        }
    }
    for (int j = (bc4 << 2) + tid; j < bc; j += 256) {
        unsigned int p = ba[j];
        int r = (int)(p & (BKT_NODES - 1));
        int s = (int)(p >> BKT_SH);
        int slot = atomicAdd(&cur[r], 1);
        if (slot < SLOTS) {
            ell_s[r * SLOTS + slot] = s;
        } else {
            int d = (b << BKT_SH) + r;
            int q = atomicAdd(ovf_meta, 1);
            if (q < OVFCAP) { ovf_dst[q] = d; ovf_src[q] = s; }
        }
    }
    // fold in bucket-capacity overflow edges (list is ~always empty)
    int m = *bovf_meta;
    if (m > BOVFCAP) m = BOVFCAP;
    for (int t = tid; t < m; t += 256) {
        int2 e = bovf[t];
        if ((e.x >> BKT_SH) == b) {
            int r = e.x & (BKT_NODES - 1);
            int slot = atomicAdd(&cur[r], 1);
            if (slot < SLOTS) {
                ell_s[r * SLOTS + slot] = e.y;
            } else {
                int q = atomicAdd(ovf_meta, 1);
                if (q < OVFCAP) { ovf_dst[q] = e.x; ovf_src[q] = e.y; }
            }
        }
    }
    __syncthreads();
    int nid0 = b << BKT_SH;
    int rows = N - nid0; if (rows > BKT_NODES) rows = BKT_NODES;
    if (rows <= 0) return;
    int4* eg = (int4*)(ell + (size_t)nid0 * SLOTS);
    const int4* es = (const int4*)ell_s;
    // dump only occupied int4 chunks (gathers never read past ceil(cnt/4) chunks)
    for (int k = tid; k < rows * (SLOTS / 4); k += 256) {
        int r = k >> 4;            // SLOTS/4 == 16 chunks per row
        int q = k & 15;
        int c = cur[r]; if (c > SLOTS) c = SLOTS;
        if (q * 4 < c) eg[k] = es[k];
    }
    for (int r = tid; r < rows; r += 256) {
        cnt[nid0 + r] = cur[r];
    }
}

// ---------------- layer 1: g = dinv * (x @ W1), 8 lanes per node, fp16 row out ----------------
__global__ __launch_bounds__(256) void layer1_kernel(const float* __restrict__ x,
                                                     const float* __restrict__ W,
                                                     const int* __restrict__ cnt,
                                                     uint4* __restrict__ g16, int N) {
    __shared__ float sW[8 * 100];
    for (int idx = threadIdx.x; idx < NF * HID; idx += 256) {
        int s = idx / 96, r = idx % 96;
        int o = r / 16, j = r % 16;
        sW[s * 100 + o * 16 + j] = W[(s * 16 + j) * HID + o];
    }
    __syncthreads();
    int t = blockIdx.x * 256 + threadIdx.x;
    int i = t >> 3;
    int sub = t & 7;
    if (t == 0) g16[N] = make_uint4(0u, 0u, 0u, 0u);    // zero row for sentinel pads
    if (i >= N) return;
    const float4* xr = (const float4*)(x + (size_t)i * NF + sub * 16);
    float4 xv0 = xr[0], xv1 = xr[1], xv2 = xr[2], xv3 = xr[3];
    const float4* wr = (const float4*)(sW + sub * 100);
    float p[HID];
#pragma unroll
    for (int o = 0; o < HID; ++o) {
        float4 w0 = wr[o * 4 + 0], w1 = wr[o * 4 + 1], w2 = wr[o * 4 + 2], w3 = wr[o * 4 + 3];
        p[o] = xv0.x * w0.x + xv0.y * w0.y + xv0.z * w0.z + xv0.w * w0.w
             + xv1.x * w1.x + xv1.y * w1.y + xv1.z * w1.z + xv1.w * w1.w
             + xv2.x * w2.x + xv2.y * w2.y + xv2.z * w2.z + xv2.w * w2.w
             + xv3.x * w3.x + xv3.y * w3.y + xv3.z * w3.z + xv3.w * w3.w;
    }
#pragma unroll
    for (int m = 1; m < 8; m <<= 1) {
#pragma unroll
        for (int o = 0; o < HID; ++o) p[o] += __shfl_xor(p[o], m);
    }
    if (sub == 0) {
        float dv = rsqrtf((float)cnt[i] + 1.0f);   // +1 self loop (dinv array deleted)
        float v[HID];
#pragma unroll
        for (int o = 0; o < HID; ++o) v[o] = dv * p[o];
        g16[i] = packh(v);
    }
}

// ---------------- chunked ELL gather, 4 sub-lanes per node (fp16 rows, padded rows) ----------------
// sub owns chunks {sub, sub+4, sub+8, sub+12} (bases sub*4, 16+sub*4, 32+sub*4, 48+sub*4).
// Rounds 0+1 cover slots 0-31 (typical deg<=32); rounds 2+3 cover 32-63. Both ell loads of
// the active rounds issue before their gathers -> per-thread MLP = 2 ell + 8 g loads.
__device__ __forceinline__ void gather4h(int ne, const int* __restrict__ er,
                                         const uint4* __restrict__ g16, int sub,
                                         __half2& a0, __half2& a1, __half2& a2) {
    int b0 = sub * 4;
    int b1 = 16 + sub * 4;
    bool act0 = b0 < ne;                 // true whenever ne >= 13 (deg floor in practice)
    bool act1 = b1 < ne;
    int4 q0, q1;
    if (act0) q0 = *(const int4*)(er + b0);
    if (act1) q1 = *(const int4*)(er + b1);
    if (act0) {
        uint4 v0 = g16[q0.x], v1 = g16[q0.y], v2 = g16[q0.z], v3 = g16[q0.w];
        addh2(a0, a1, a2, v0); addh2(a0, a1, a2, v1);
        addh2(a0, a1, a2, v2); addh2(a0, a1, a2, v3);
    }
    if (act1) {
        uint4 v0 = g16[q1.x], v1 = g16[q1.y], v2 = g16[q1.z], v3 = g16[q1.w];
        addh2(a0, a1, a2, v0); addh2(a0, a1, a2, v1);
        addh2(a0, a1, a2, v2); addh2(a0, a1, a2, v3);
    }
    if (ne > 32) {                       // ~46% of nodes reach round 2; round 3 ~0.3%
        int b2 = 32 + sub * 4;
        int b3 = 48 + sub * 4;
        bool act2 = b2 < ne;
        bool act3 = b3 < ne;
        int4 q2, q3;
        if (act2) q2 = *(const int4*)(er + b2);
        if (act3) q3 = *(const int4*)(er + b3);
        if (act2) {
            uint4 v0 = g16[q2.x], v1 = g16[q2.y], v2 = g16[q2.z], v3 = g16[q2.w];
            addh2(a0, a1, a2, v0); addh2(a0, a1, a2, v1);
            addh2(a0, a1, a2, v2); addh2(a0, a1, a2, v3);
        }
        if (act3) {
            uint4 v0 = g16[q3.x], v1 = g16[q3.y], v2 = g16[q3.z], v3 = g16[q3.w];
            addh2(a0, a1, a2, v0); addh2(a0, a1, a2, v1);
            addh2(a0, a1, a2, v2); addh2(a0, a1, a2, v3);
        }
    }
}

// ---------------- fused: gather + epilogue (+ next matmul), 4 lanes per node ----------------
// PREP=0: gout = dinv * (relu(dinv*(sum+self)+b) @ W)
// PREP=1: gout = dinv *  relu(dinv*(sum+self)+b)
template<int PREP>
__global__ __launch_bounds__(256) void gcn_layer4_kernel(
        const int* __restrict__ cnt, const int* __restrict__ ell,
        const int* __restrict__ ovf_meta, const int* __restrict__ ovf_dst,
        const int* __restrict__ ovf_src,
        const uint4* __restrict__ gin, uint4* __restrict__ gout,
        const float* __restrict__ W, const float* __restrict__ b, int N) {
    int t = blockIdx.x * 256 + threadIdx.x;
    int i = t >> 2;
    int sub = t & 3;
    if (t == 0) gout[N] = make_uint4(0u, 0u, 0u, 0u);   // keep zero row alive
    if (i >= N) return;
    int n = cnt[i];
    int ne = n < SLOTS ? n : SLOTS;
    const int* er = ell + (size_t)i * SLOTS;
    __half2 a0 = __float2half2_rn(0.f), a1 = a0, a2 = a0;
    gather4h(ne, er, gin, sub, a0, a1, a2);
    // self-loop term, added exactly once across the subgroup
    if (sub == 0) addh2(a0, a1, a2, gin[i]);
    if (n > SLOTS && sub == 2) {  // ~never taken; correct fallback for deg>SLOTS
        int m = ovf_meta[0];
        m = m < OVFCAP ? m : OVFCAP;
        for (int tt = 0; tt < m; ++tt) {
            if (ovf_dst[tt] == i) addh2(a0, a1, a2, gin[ovf_src[tt]]);
        }
    }
    // packed butterfly over 4 lanes (all end with the total)
#pragma unroll
    for (int m = 1; m < 4; m <<= 1) {
        a0 = __hadd2(a0, shfl_xor_h2(a0, m));
        a1 = __hadd2(a1, shfl_xor_h2(a1, m));
        a2 = __hadd2(a2, shfl_xor_h2(a2, m));
    }
    if (sub != 0) return;
    float2 f0 = __half22float2(a0), f1 = __half22float2(a1), f2 = __half22float2(a2);
    float acc[HID] = { f0.x, f0.y, f1.x, f1.y, f2.x, f2.y };
    float dv = rsqrtf((float)n + 1.0f);   // dinv recomputed (bit-identical across kernels)
    float h[HID];
#pragma unroll
    for (int f = 0; f < HID; ++f) {
        float u = dv * acc[f] + b[f];
        h[f] = u > 0.0f ? u : 0.0f;
    }
    float o[HID];
    if (PREP) {
#pragma unroll
        for (int f = 0; f < HID; ++f) o[f] = dv * h[f];
    } else {
#pragma unroll
        for (int fo = 0; fo < HID; ++fo) {
            float s = 0.0f;
#pragma unroll
            for (int fi = 0; fi < HID; ++fi) s += h[fi] * W[fi * HID + fo];
            o[fo] = dv * s;
        }
    }
    gout[i] = packh(o);
}

// ---------------- pool: gather conv7 + Wf + relu + LDS mean-pool, 4 lanes per node ----------------
__global__ __launch_bounds__(256) void pool_kernel(
        const int* __restrict__ cnt, const int* __restrict__ ell,
        const int* __restrict__ ovf_meta, const int* __restrict__ ovf_dst,
        const int* __restrict__ ovf_src,
        const uint4* __restrict__ gin, const int* __restrict__ batch,
        const float* __restrict__ Wf, const float* __restrict__ bf,
        float* __restrict__ pooled, float* __restrict__ gcnt, int N) {
    __shared__ float sp[NG * NC];
    __shared__ float sc[NG];
    __shared__ int srange[2];
    for (int k = threadIdx.x; k < NG * NC; k += 256) sp[k] = 0.0f;
    if (threadIdx.x < NG) sc[threadIdx.x] = 0.0f;
    int start = blockIdx.x * 64;           // 64 nodes per block (256 thr / 4)
    int endi = min(start + 64, N) - 1;
    if (threadIdx.x == 0 && start < N) {
        srange[0] = batch[start];   // batch is sorted
        srange[1] = batch[endi];
    }
    __syncthreads();
    int t = blockIdx.x * 256 + threadIdx.x;
    int i = t >> 2;
    int sub = t & 3;
    if (i < N) {
        int n = cnt[i];
        int ne = n < SLOTS ? n : SLOTS;
        const int* er = ell + (size_t)i * SLOTS;
        __half2 a0 = __float2half2_rn(0.f), a1 = a0, a2 = a0;
        gather4h(ne, er, gin, sub, a0, a1, a2);
        if (sub == 0) addh2(a0, a1, a2, gin[i]);
        if (n > SLOTS && sub == 2) {
            int m = ovf_meta[0];
            m = m < OVFCAP ? m : OVFCAP;
            for (int tt = 0; tt < m; ++tt) {
                if (ovf_dst[tt] == i) addh2(a0, a1, a2, gin[ovf_src[tt]]);
            }
        }
#pragma unroll
        for (int m = 1; m < 4; m <<= 1) {
            a0 = __hadd2(a0, shfl_xor_h2(a0, m));
            a1 = __hadd2(a1, shfl_xor_h2(a1, m));
            a2 = __hadd2(a2, shfl_xor_h2(a2, m));
        }
        if (sub == 0) {
            float2 f0 = __half22float2(a0), f1 = __half22float2(a1), f2 = __half22float2(a2);
            float acc[HID] = { f0.x, f0.y, f1.x, f1.y, f2.x, f2.y };
            float dv = rsqrtf((float)n + 1.0f);
            float u[HID];
#pragma unroll
            for (int f = 0; f < HID; ++f) u[f] = dv * acc[f];
            int bg = batch[i];
#pragma unroll
            for (int c = 0; c < NC; ++c) {
                float v = bf[c];
#pragma unroll
                for (int f = 0; f < HID; ++f) v += u[f] * Wf[f * NC + c];
                v = v > 0.0f ? v : 0.0f;
                atomicAdd(&sp[bg * NC + c], v);
            }
            atomicAdd(&sc[bg], 1.0f);
        }
    }
    __syncthreads();
    if (start >= N) return;
    int bmin = srange[0], bmax = srange[1];
    int rows = bmax - bmin + 1;
    for (int k = threadIdx.x; k < rows * NC; k += 256) {
        int r = bmin + k / NC, c = k % NC;
        float v = sp[r * NC + c];
        if (v != 0.0f) atomicAdd(&pooled[r * NC + c], v);
    }
    for (int k = threadIdx.x; k < rows; k += 256) {
        float v = sc[bmin + k];
        if (v != 0.0f) atomicAdd(&gcnt[bmin + k], v);
    }
}

// ---------------- mean + log_softmax ----------------
__global__ void logsm_kernel(const float* __restrict__ pooled, const float* __restrict__ gcnt,
                             float* __restrict__ out) {
    int gidx = threadIdx.x;
    if (gidx >= NG) return;
    float c = gcnt[gidx];
    c = c > 1.0f ? c : 1.0f;
    float v[NC];
    float m = -1e30f;
#pragma unroll
    for (int k = 0; k < NC; ++k) {
        v[k] = pooled[gidx * NC + k] / c;
        m = v[k] > m ? v[k] : m;
    }
    float s = 0.0f;
#pragma unroll
    for (int k = 0; k < NC; ++k) s += expf(v[k] - m);
    float ls = logf(s);
#pragma unroll
    for (int k = 0; k < NC; ++k) out[gidx * NC + k] = v[k] - m - ls;
}

extern "C" void kernel_launch(void* const* d_in, const int* in_sizes, int n_in,
                              void* d_out, int out_size, void* d_ws, size_t ws_size,
                              hipStream_t stream) {
    const float* x     = (const float*)d_in[0];
    const int*   ei    = (const int*)d_in[1];
    const int*   batch = (const int*)d_in[2];
    const float* W[7];
    const float* b[7];
    for (int l = 0; l < 7; ++l) {
        W[l] = (const float*)d_in[3 + 2 * l];
        b[l] = (const float*)d_in[4 + 2 * l];
    }
    const int N = in_sizes[2];
    const int E = in_sizes[1] / 2;
    const int nbk = (N + BKT_NODES - 1) >> BKT_SH;
    const int* src = ei;
    const int* dst = ei + E;
    float* out = (float*)d_out;

    // workspace layout (16B-aligned blocks)
    char* wp = (char*)d_ws;
    int* bucket_cursor = (int*)wp;  wp += (size_t)NBK_MAX * 4;
    int* ovf_meta  = (int*)wp;      wp += 16;
    int* bovf_meta = (int*)wp;      wp += 16;   // metas contiguous with cursor -> one init span
    int* ovf_dst   = (int*)wp;      wp += OVFCAP * 4;
    int* ovf_src   = (int*)wp;      wp += OVFCAP * 4;
    int2* bovf     = (int2*)wp;     wp += (size_t)BOVFCAP * 8;
    int* cnt       = (int*)wp;      wp += (((size_t)N * 4 + 15) & ~15ull);
    uint4* g_a     = (uint4*)wp;    wp += (size_t)(N + 1) * 16;   // +1: zero row for pads
    uint4* g_b     = (uint4*)wp;    wp += (size_t)(N + 1) * 16;
    float* pooled  = (float*)wp;    wp += NG * NC * 4;            // gcnt follows contiguously
    float* gcnt    = (float*)wp;    wp += (((size_t)NG * 4 + 15) & ~15ull);
    int* ell       = (int*)wp;      wp += (size_t)N * SLOTS * 4;
    unsigned int* bucket_arr = (unsigned int*)wp;  wp += (size_t)nbk * BCAP * 4;

    const int BT = 256;
    int bn8 = ((size_t)N * 8 + BT - 1) / BT;
    int bn4 = ((size_t)N * 4 + BT - 1) / BT;
    int bp1 = (E + EPB - 1) / EPB;

    init_kernel<<<(NBK_MAX + 8 + NG * NC + NG + BT - 1) / BT, BT, 0, stream>>>(bucket_cursor, pooled);

    bucket_scatter_kernel<<<bp1, BT, 0, stream>>>(src, dst, E, nbk, bucket_cursor,
                                                  bucket_arr, bovf_meta, bovf);
    ell_build_kernel<<<nbk, BT, 0, stream>>>(bucket_arr, bucket_cursor, bovf_meta, bovf,
                                             ell, cnt, ovf_meta, ovf_dst, ovf_src, N);

    layer1_kernel<<<bn8, BT, 0, stream>>>(x, W[0], cnt, g_a, N);

    // 5 mid layers: (b1,W2) .. (b5,W6), alternating g buffers
    gcn_layer4_kernel<0><<<bn4, BT, 0, stream>>>(cnt, ell, ovf_meta, ovf_dst, ovf_src, g_a, g_b, W[1], b[0], N);
    gcn_layer4_kernel<0><<<bn4, BT, 0, stream>>>(cnt, ell, ovf_meta, ovf_dst, ovf_src, g_b, g_a, W[2], b[1], N);
    gcn_layer4_kernel<0><<<bn4, BT, 0, stream>>>(cnt, ell, ovf_meta, ovf_dst, ovf_src, g_a, g_b, W[3], b[2], N);
    gcn_layer4_kernel<0><<<bn4, BT, 0, stream>>>(cnt, ell, ovf_meta, ovf_dst, ovf_src, g_b, g_a, W[4], b[3], N);
    gcn_layer4_kernel<0><<<bn4, BT, 0, stream>>>(cnt, ell, ovf_meta, ovf_dst, ovf_src, g_a, g_b, W[5], b[4], N);
    // layer 6 epilogue (b6), no next W
    gcn_layer4_kernel<1><<<bn4, BT, 0, stream>>>(cnt, ell, ovf_meta, ovf_dst, ovf_src, g_b, g_a, nullptr, b[5], N);
    // conv7 gather + Wf + bf + relu + pool
    pool_kernel<<<bn4, BT, 0, stream>>>(cnt, ell, ovf_meta, ovf_dst, ovf_src, g_a, batch, W[6], b[6], pooled, gcnt, N);
    logsm_kernel<<<1, 64, 0, stream>>>(pooled, gcnt, out);
}

// Round 10
// 314.288 us; speedup vs baseline: 1.7587x; 1.0071x over previous
//
#include <hip/hip_runtime.h>
#include <hip/hip_bf16.h>
#include <hip/hip_fp16.h>
#include <math.h>

#define NF     128
#define HID    6
#define NC     10
#define NG     64
#define SLOTS  64     // ELL row capacity (deg ~ Poisson(32); P(deg>64) ~ 4e-7/node)
#define OVFCAP 8192

// bucket build params
#define BKT_SH    7
#define BKT_NODES 128
#define NBK_MAX   1024     // supports N <= 131072
#define EPB       4096     // edges per phase-1 block (512 thr x 8)
#define BCAP      5120     // per-bucket capacity (mean 4096, +16 sigma)
#define BOVFCAP   4096

// v9 = v8 (316.5us) + 512-thread build kernels.
// r1 lesson: halving EPB doubled block count -> doubled per-block fixed costs, lost.
// This halves the per-thread serial chains (8 atomics / 8 stage writes / 8 copy-out
// iters instead of 16) while keeping 782 blocks, the same EPB, the same reservation
// totals, and the same copy-out run lengths (WRITE_SIZE invariant ~29MB). Occupancy
// 12 -> 24 waves/CU. Same for ell_build (scatter's structural twin, unprofiled).

// g row: 6 values as fp16, padded to 16B (8 halves) -> ONE dwordx4 per neighbor.
__device__ __forceinline__ void addh2(__half2& a0, __half2& a1, __half2& a2, uint4 q) {
    const __half2* h = (const __half2*)&q;
    a0 = __hadd2(a0, h[0]);
    a1 = __hadd2(a1, h[1]);
    a2 = __hadd2(a2, h[2]);
}

__device__ __forceinline__ __half2 shfl_xor_h2(__half2 v, int m) {
    union { __half2 h; unsigned int u; } a;
    a.h = v;
    a.u = __shfl_xor(a.u, m);
    return a.h;
}

__device__ __forceinline__ uint4 packh(const float* v) {
    uint4 q;
    __half2* h = (__half2*)&q;
    h[0] = __floats2half2_rn(v[0], v[1]);
    h[1] = __floats2half2_rn(v[2], v[3]);
    h[2] = __floats2half2_rn(v[4], v[5]);
    h[3] = __floats2half2_rn(0.f, 0.f);
    return q;
}

// ---------------- init: zero cursor+metas and pooled+gcnt in one dispatch ----------------
__global__ __launch_bounds__(256) void init_kernel(int* __restrict__ bucket_cursor,
                                                   float* __restrict__ pooled) {
    int t = blockIdx.x * 256 + threadIdx.x;
    if (t < NBK_MAX + 8) bucket_cursor[t] = 0;            // cursor + ovf_meta + bovf_meta
    int p = t - (NBK_MAX + 8);
    if (p >= 0 && p < NG * NC + NG) pooled[p] = 0.0f;     // pooled + gcnt (contiguous)
}

// ---------------- phase 1: bin edges by dst>>7, rank-from-count, staged coalesced copy-out ----------------
// 512 threads, 8 edges/thread.
__global__ __launch_bounds__(512) void bucket_scatter_kernel(
        const int* __restrict__ src, const int* __restrict__ dst, int E, int nbk,
        int* __restrict__ bucket_cursor, unsigned int* __restrict__ bucket_arr,
        int* __restrict__ bovf_meta, int2* __restrict__ bovf) {
    __shared__ int cntL[NBK_MAX];
    __shared__ int offs[NBK_MAX];
    __shared__ int gb[NBK_MAX];
    __shared__ int wtot[8];
    __shared__ unsigned int stage[EPB];
    __shared__ unsigned int stage_gi[EPB];
    int tid = threadIdx.x;
    for (int k = tid; k < NBK_MAX; k += 512) cntL[k] = 0;
    __syncthreads();                                     // B1
    int e0 = blockIdx.x * EPB;
    int cnt_e = E - e0; if (cnt_e > EPB) cnt_e = EPB;
    int sreg[8], dreg[8], rank[8];
    // pass A: load edges + LDS-atomic rank (atomic return IS the local rank)
    if (cnt_e == EPB && (E & 3) == 0) {
        const int4* s4p = (const int4*)(src + e0);
        const int4* d4p = (const int4*)(dst + e0);
#pragma unroll
        for (int k = 0; k < 2; ++k) {
            int4 sv = s4p[k * 512 + tid];
            int4 dv = d4p[k * 512 + tid];
            sreg[4*k+0] = sv.x; sreg[4*k+1] = sv.y; sreg[4*k+2] = sv.z; sreg[4*k+3] = sv.w;
            dreg[4*k+0] = dv.x; dreg[4*k+1] = dv.y; dreg[4*k+2] = dv.z; dreg[4*k+3] = dv.w;
        }
#pragma unroll
        for (int k = 0; k < 8; ++k) rank[k] = atomicAdd(&cntL[dreg[k] >> BKT_SH], 1);
    } else {
#pragma unroll
        for (int k = 0; k < 8; ++k) {
            int e = e0 + k * 512 + tid;
            if (e < E) {
                dreg[k] = dst[e]; sreg[k] = src[e];
                rank[k] = atomicAdd(&cntL[dreg[k] >> BKT_SH], 1);
            } else dreg[k] = -1;
        }
    }
    __syncthreads();                                     // B2
    // exclusive scan over 1024 bucket counts: 2/thread + wave shfl-scan + wave-total combine
    int base = tid * 2;
    int c0 = cntL[base], c1 = cntL[base + 1];
    int tsum = c0 + c1;
    int lane = tid & 63, wv = tid >> 6;                  // 8 waves
    int v = tsum;
#pragma unroll
    for (int off = 1; off < 64; off <<= 1) {
        int u = __shfl_up(v, off);
        if (lane >= off) v += u;
    }
    if (lane == 63) wtot[wv] = v;
    __syncthreads();                                     // B3
    int wbase = 0;
    for (int w = 0; w < wv; ++w) wbase += wtot[w];
    int ex = wbase + v - tsum;
    offs[base]     = ex;
    offs[base + 1] = ex + c0;
    // reserve global spans (one atomic per non-empty bucket per block)
    for (int bb = tid; bb < nbk; bb += 512) {
        int c = cntL[bb];
        if (c > 0) gb[bb] = atomicAdd(&bucket_cursor[bb], c);
    }
    __syncthreads();                                     // B4
    // pass B: stage payload AND final global index (no binary search needed later)
#pragma unroll
    for (int k = 0; k < 8; ++k) {
        int d = dreg[k];
        if (d < 0) continue;
        int b = d >> BKT_SH;
        int pos = offs[b] + rank[k];
        unsigned int p = (unsigned int)(d & (BKT_NODES - 1)) | ((unsigned int)sreg[k] << BKT_SH);
        int grel = gb[b] + rank[k];
        stage[pos] = p;
        if (grel < BCAP) {
            stage_gi[pos] = (unsigned int)b * BCAP + (unsigned int)grel;
        } else {  // bucket capacity overflow (~never)
            stage_gi[pos] = 0xFFFFFFFFu;
            int p2 = atomicAdd(bovf_meta, 1);
            if (p2 < BOVFCAP) bovf[p2] = make_int2(d, sreg[k]);
        }
    }
    __syncthreads();                                     // B5
    // copy out: consecutive j within a bucket run -> consecutive gi -> coalesced writes
    for (int j = tid; j < cnt_e; j += 512) {
        unsigned int gi = stage_gi[j];
        if (gi != 0xFFFFFFFFu) bucket_arr[gi] = stage[j];
    }
}

// ---------------- phase 2: per-bucket ELL build in LDS, pruned coalesced dump ----------------
// 512 threads, ~8 edges/thread. ELL rows padded (within the last occupied int4 chunk)
// with sentinel index N -> gathers add 4 unconditionally.
__global__ __launch_bounds__(512) void ell_build_kernel(
        const unsigned int* __restrict__ bucket_arr, const int* __restrict__ bucket_cursor,
        const int* __restrict__ bovf_meta, const int2* __restrict__ bovf,
        int* __restrict__ ell, int* __restrict__ cnt,
        int* __restrict__ ovf_meta, int* __restrict__ ovf_dst, int* __restrict__ ovf_src,
        int N) {
    __shared__ int ell_s[BKT_NODES * SLOTS];   // 32KB
    __shared__ int cur[BKT_NODES];
    int b = blockIdx.x;
    int tid = threadIdx.x;
    if (tid < BKT_NODES) cur[tid] = 0;
    {   // int4 sentinel init
        int4* e4 = (int4*)ell_s;
        int4 sv = make_int4(N, N, N, N);
        for (int k = tid; k < BKT_NODES * SLOTS / 4; k += 512) e4[k] = sv;
    }
    __syncthreads();
    int bc = bucket_cursor[b];
    if (bc > BCAP) bc = BCAP;
    const unsigned int* ba = bucket_arr + (size_t)b * BCAP;
    int bc4 = bc >> 2;
    const uint4* ba4 = (const uint4*)ba;
    for (int j = tid; j < bc4; j += 512) {
        uint4 pv = ba4[j];
        unsigned int ps[4] = { pv.x, pv.y, pv.z, pv.w };
#pragma unroll
        for (int q = 0; q < 4; ++q) {
            unsigned int p = ps[q];
            int r = (int)(p & (BKT_NODES - 1));
            int s = (int)(p >> BKT_SH);
            int slot = atomicAdd(&cur[r], 1);
            if (slot < SLOTS) {
                ell_s[r * SLOTS + slot] = s;
            } else {  // node degree overflow (~never)
                int d = (b << BKT_SH) + r;
                int qq = atomicAdd(ovf_meta, 1);
                if (qq < OVFCAP) { ovf_dst[qq] = d; ovf_src[qq] = s; }
            }
        }
    }
    for (int j = (bc4 << 2) + tid; j < bc; j += 512) {
        unsigned int p = ba[j];
        int r = (int)(p & (BKT_NODES - 1));
        int s = (int)(p >> BKT_SH);
        int slot = atomicAdd(&cur[r], 1);
        if (slot < SLOTS) {
            ell_s[r * SLOTS + slot] = s;
        } else {
            int d = (b << BKT_SH) + r;
            int q = atomicAdd(ovf_meta, 1);
            if (q < OVFCAP) { ovf_dst[q] = d; ovf_src[q] = s; }
        }
    }
    // fold in bucket-capacity overflow edges (list is ~always empty)
    int m = *bovf_meta;
    if (m > BOVFCAP) m = BOVFCAP;
    for (int t = tid; t < m; t += 512) {
        int2 e = bovf[t];
        if ((e.x >> BKT_SH) == b) {
            int r = e.x & (BKT_NODES - 1);
            int slot = atomicAdd(&cur[r], 1);
            if (slot < SLOTS) {
                ell_s[r * SLOTS + slot] = e.y;
            } else {
                int q = atomicAdd(ovf_meta, 1);
                if (q < OVFCAP) { ovf_dst[q] = e.x; ovf_src[q] = e.y; }
            }
        }
    }
    __syncthreads();
    int nid0 = b << BKT_SH;
    int rows = N - nid0; if (rows > BKT_NODES) rows = BKT_NODES;
    if (rows <= 0) return;
    int4* eg = (int4*)(ell + (size_t)nid0 * SLOTS);
    const int4* es = (const int4*)ell_s;
    // dump only occupied int4 chunks (gathers never read past ceil(cnt/4) chunks)
    for (int k = tid; k < rows * (SLOTS / 4); k += 512) {
        int r = k >> 4;            // SLOTS/4 == 16 chunks per row
        int q = k & 15;
        int c = cur[r]; if (c > SLOTS) c = SLOTS;
        if (q * 4 < c) eg[k] = es[k];
    }
    for (int r = tid; r < rows; r += 512) {
        cnt[nid0 + r] = cur[r];
    }
}

// ---------------- layer 1: g = dinv * (x @ W1), 8 lanes per node, fp16 row out ----------------
__global__ __launch_bounds__(256) void layer1_kernel(const float* __restrict__ x,
                                                     const float* __restrict__ W,
                                                     const int* __restrict__ cnt,
                                                     uint4* __restrict__ g16, int N) {
    __shared__ float sW[8 * 100];
    for (int idx = threadIdx.x; idx < NF * HID; idx += 256) {
        int s = idx / 96, r = idx % 96;
        int o = r / 16, j = r % 16;
        sW[s * 100 + o * 16 + j] = W[(s * 16 + j) * HID + o];
    }
    __syncthreads();
    int t = blockIdx.x * 256 + threadIdx.x;
    int i = t >> 3;
    int sub = t & 7;
    if (t == 0) g16[N] = make_uint4(0u, 0u, 0u, 0u);    // zero row for sentinel pads
    if (i >= N) return;
    const float4* xr = (const float4*)(x + (size_t)i * NF + sub * 16);
    float4 xv0 = xr[0], xv1 = xr[1], xv2 = xr[2], xv3 = xr[3];
    const float4* wr = (const float4*)(sW + sub * 100);
    float p[HID];
#pragma unroll
    for (int o = 0; o < HID; ++o) {
        float4 w0 = wr[o * 4 + 0], w1 = wr[o * 4 + 1], w2 = wr[o * 4 + 2], w3 = wr[o * 4 + 3];
        p[o] = xv0.x * w0.x + xv0.y * w0.y + xv0.z * w0.z + xv0.w * w0.w
             + xv1.x * w1.x + xv1.y * w1.y + xv1.z * w1.z + xv1.w * w1.w
             + xv2.x * w2.x + xv2.y * w2.y + xv2.z * w2.z + xv2.w * w2.w
             + xv3.x * w3.x + xv3.y * w3.y + xv3.z * w3.z + xv3.w * w3.w;
    }
#pragma unroll
    for (int m = 1; m < 8; m <<= 1) {
#pragma unroll
        for (int o = 0; o < HID; ++o) p[o] += __shfl_xor(p[o], m);
    }
    if (sub == 0) {
        float dv = rsqrtf((float)cnt[i] + 1.0f);   // +1 self loop (dinv array deleted)
        float v[HID];
#pragma unroll
        for (int o = 0; o < HID; ++o) v[o] = dv * p[o];
        g16[i] = packh(v);
    }
}

// ---------------- chunked ELL gather, 4 sub-lanes per node (fp16 rows, padded rows) ----------------
// sub owns chunks {sub, sub+4, sub+8, sub+12} (bases sub*4, 16+sub*4, 32+sub*4, 48+sub*4).
__device__ __forceinline__ void gather4h(int ne, const int* __restrict__ er,
                                         const uint4* __restrict__ g16, int sub,
                                         __half2& a0, __half2& a1, __half2& a2) {
    int b0 = sub * 4;
    int b1 = 16 + sub * 4;
    bool act0 = b0 < ne;
    bool act1 = b1 < ne;
    int4 q0, q1;
    if (act0) q0 = *(const int4*)(er + b0);
    if (act1) q1 = *(const int4*)(er + b1);
    if (act0) {
        uint4 v0 = g16[q0.x], v1 = g16[q0.y], v2 = g16[q0.z], v3 = g16[q0.w];
        addh2(a0, a1, a2, v0); addh2(a0, a1, a2, v1);
        addh2(a0, a1, a2, v2); addh2(a0, a1, a2, v3);
    }
    if (act1) {
        uint4 v0 = g16[q1.x], v1 = g16[q1.y], v2 = g16[q1.z], v3 = g16[q1.w];
        addh2(a0, a1, a2, v0); addh2(a0, a1, a2, v1);
        addh2(a0, a1, a2, v2); addh2(a0, a1, a2, v3);
    }
    if (ne > 32) {
        int b2 = 32 + sub * 4;
        int b3 = 48 + sub * 4;
        bool act2 = b2 < ne;
        bool act3 = b3 < ne;
        int4 q2, q3;
        if (act2) q2 = *(const int4*)(er + b2);
        if (act3) q3 = *(const int4*)(er + b3);
        if (act2) {
            uint4 v0 = g16[q2.x], v1 = g16[q2.y], v2 = g16[q2.z], v3 = g16[q2.w];
            addh2(a0, a1, a2, v0); addh2(a0, a1, a2, v1);
            addh2(a0, a1, a2, v2); addh2(a0, a1, a2, v3);
        }
        if (act3) {
            uint4 v0 = g16[q3.x], v1 = g16[q3.y], v2 = g16[q3.z], v3 = g16[q3.w];
            addh2(a0, a1, a2, v0); addh2(a0, a1, a2, v1);
            addh2(a0, a1, a2, v2); addh2(a0, a1, a2, v3);
        }
    }
}

// ---------------- fused: gather + epilogue (+ next matmul), 4 lanes per node ----------------
// PREP=0: gout = dinv * (relu(dinv*(sum+self)+b) @ W)
// PREP=1: gout = dinv *  relu(dinv*(sum+self)+b)
template<int PREP>
__global__ __launch_bounds__(256) void gcn_layer4_kernel(
        const int* __restrict__ cnt, const int* __restrict__ ell,
        const int* __restrict__ ovf_meta, const int* __restrict__ ovf_dst,
        const int* __restrict__ ovf_src,
        const uint4* __restrict__ gin, uint4* __restrict__ gout,
        const float* __restrict__ W, const float* __restrict__ b, int N) {
    int t = blockIdx.x * 256 + threadIdx.x;
    int i = t >> 2;
    int sub = t & 3;
    if (t == 0) gout[N] = make_uint4(0u, 0u, 0u, 0u);   // keep zero row alive
    if (i >= N) return;
    int n = cnt[i];
    int ne = n < SLOTS ? n : SLOTS;
    const int* er = ell + (size_t)i * SLOTS;
    __half2 a0 = __float2half2_rn(0.f), a1 = a0, a2 = a0;
    gather4h(ne, er, gin, sub, a0, a1, a2);
    // self-loop term, added exactly once across the subgroup
    if (sub == 0) addh2(a0, a1, a2, gin[i]);
    if (n > SLOTS && sub == 2) {  // ~never taken; correct fallback for deg>SLOTS
        int m = ovf_meta[0];
        m = m < OVFCAP ? m : OVFCAP;
        for (int tt = 0; tt < m; ++tt) {
            if (ovf_dst[tt] == i) addh2(a0, a1, a2, gin[ovf_src[tt]]);
        }
    }
    // packed butterfly over 4 lanes (all end with the total)
#pragma unroll
    for (int m = 1; m < 4; m <<= 1) {
        a0 = __hadd2(a0, shfl_xor_h2(a0, m));
        a1 = __hadd2(a1, shfl_xor_h2(a1, m));
        a2 = __hadd2(a2, shfl_xor_h2(a2, m));
    }
    if (sub != 0) return;
    float2 f0 = __half22float2(a0), f1 = __half22float2(a1), f2 = __half22float2(a2);
    float acc[HID] = { f0.x, f0.y, f1.x, f1.y, f2.x, f2.y };
    float dv = rsqrtf((float)n + 1.0f);   // dinv recomputed (bit-identical across kernels)
    float h[HID];
#pragma unroll
    for (int f = 0; f < HID; ++f) {
        float u = dv * acc[f] + b[f];
        h[f] = u > 0.0f ? u : 0.0f;
    }
    float o[HID];
    if (PREP) {
#pragma unroll
        for (int f = 0; f < HID; ++f) o[f] = dv * h[f];
    } else {
#pragma unroll
        for (int fo = 0; fo < HID; ++fo) {
            float s = 0.0f;
#pragma unroll
            for (int fi = 0; fi < HID; ++fi) s += h[fi] * W[fi * HID + fo];
            o[fo] = dv * s;
        }
    }
    gout[i] = packh(o);
}

// ---------------- pool: gather conv7 + Wf + relu + LDS mean-pool, 4 lanes per node ----------------
__global__ __launch_bounds__(256) void pool_kernel(
        const int* __restrict__ cnt, const int* __restrict__ ell,
        const int* __restrict__ ovf_meta, const int* __restrict__ ovf_dst,
        const int* __restrict__ ovf_src,
        const uint4* __restrict__ gin, const int* __restrict__ batch,
        const float* __restrict__ Wf, const float* __restrict__ bf,
        float* __restrict__ pooled, float* __restrict__ gcnt, int N) {
    __shared__ float sp[NG * NC];
    __shared__ float sc[NG];
    __shared__ int srange[2];
    for (int k = threadIdx.x; k < NG * NC; k += 256) sp[k] = 0.0f;
    if (threadIdx.x < NG) sc[threadIdx.x] = 0.0f;
    int start = blockIdx.x * 64;           // 64 nodes per block (256 thr / 4)
    int endi = min(start + 64, N) - 1;
    if (threadIdx.x == 0 && start < N) {
        srange[0] = batch[start];   // batch is sorted
        srange[1] = batch[endi];
    }
    __syncthreads();
    int t = blockIdx.x * 256 + threadIdx.x;
    int i = t >> 2;
    int sub = t & 3;
    if (i < N) {
        int n = cnt[i];
        int ne = n < SLOTS ? n : SLOTS;
        const int* er = ell + (size_t)i * SLOTS;
        __half2 a0 = __float2half2_rn(0.f), a1 = a0, a2 = a0;
        gather4h(ne, er, gin, sub, a0, a1, a2);
        if (sub == 0) addh2(a0, a1, a2, gin[i]);
        if (n > SLOTS && sub == 2) {
            int m = ovf_meta[0];
            m = m < OVFCAP ? m : OVFCAP;
            for (int tt = 0; tt < m; ++tt) {
                if (ovf_dst[tt] == i) addh2(a0, a1, a2, gin[ovf_src[tt]]);
            }
        }
#pragma unroll
        for (int m = 1; m < 4; m <<= 1) {
            a0 = __hadd2(a0, shfl_xor_h2(a0, m));
            a1 = __hadd2(a1, shfl_xor_h2(a1, m));
            a2 = __hadd2(a2, shfl_xor_h2(a2, m));
        }
        if (sub == 0) {
            float2 f0 = __half22float2(a0), f1 = __half22float2(a1), f2 = __half22float2(a2);
            float acc[HID] = { f0.x, f0.y, f1.x, f1.y, f2.x, f2.y };
            float dv = rsqrtf((float)n + 1.0f);
            float u[HID];
#pragma unroll
            for (int f = 0; f < HID; ++f) u[f] = dv * acc[f];
            int bg = batch[i];
#pragma unroll
            for (int c = 0; c < NC; ++c) {
                float v = bf[c];
#pragma unroll
                for (int f = 0; f < HID; ++f) v += u[f] * Wf[f * NC + c];
                v = v > 0.0f ? v : 0.0f;
                atomicAdd(&sp[bg * NC + c], v);
            }
            atomicAdd(&sc[bg], 1.0f);
        }
    }
    __syncthreads();
    if (start >= N) return;
    int bmin = srange[0], bmax = srange[1];
    int rows = bmax - bmin + 1;
    for (int k = threadIdx.x; k < rows * NC; k += 256) {
        int r = bmin + k / NC, c = k % NC;
        float v = sp[r * NC + c];
        if (v != 0.0f) atomicAdd(&pooled[r * NC + c], v);
    }
    for (int k = threadIdx.x; k < rows; k += 256) {
        float v = sc[bmin + k];
        if (v != 0.0f) atomicAdd(&gcnt[bmin + k], v);
    }
}

// ---------------- mean + log_softmax ----------------
__global__ void logsm_kernel(const float* __restrict__ pooled, const float* __restrict__ gcnt,
                             float* __restrict__ out) {
    int gidx = threadIdx.x;
    if (gidx >= NG) return;
    float c = gcnt[gidx];
    c = c > 1.0f ? c : 1.0f;
    float v[NC];
    float m = -1e30f;
#pragma unroll
    for (int k = 0; k < NC; ++k) {
        v[k] = pooled[gidx * NC + k] / c;
        m = v[k] > m ? v[k] : m;
    }
    float s = 0.0f;
#pragma unroll
    for (int k = 0; k < NC; ++k) s += expf(v[k] - m);
    float ls = logf(s);
#pragma unroll
    for (int k = 0; k < NC; ++k) out[gidx * NC + k] = v[k] - m - ls;
}

extern "C" void kernel_launch(void* const* d_in, const int* in_sizes, int n_in,
                              void* d_out, int out_size, void* d_ws, size_t ws_size,
                              hipStream_t stream) {
    const float* x     = (const float*)d_in[0];
    const int*   ei    = (const int*)d_in[1];
    const int*   batch = (const int*)d_in[2];
    const float* W[7];
    const float* b[7];
    for (int l = 0; l < 7; ++l) {
        W[l] = (const float*)d_in[3 + 2 * l];
        b[l] = (const float*)d_in[4 + 2 * l];
    }
    const int N = in_sizes[2];
    const int E = in_sizes[1] / 2;
    const int nbk = (N + BKT_NODES - 1) >> BKT_SH;
    const int* src = ei;
    const int* dst = ei + E;
    float* out = (float*)d_out;

    // workspace layout (16B-aligned blocks)
    char* wp = (char*)d_ws;
    int* bucket_cursor = (int*)wp;  wp += (size_t)NBK_MAX * 4;
    int* ovf_meta  = (int*)wp;      wp += 16;
    int* bovf_meta = (int*)wp;      wp += 16;   // metas contiguous with cursor -> one init span
    int* ovf_dst   = (int*)wp;      wp += OVFCAP * 4;
    int* ovf_src   = (int*)wp;      wp += OVFCAP * 4;
    int2* bovf     = (int2*)wp;     wp += (size_t)BOVFCAP * 8;
    int* cnt       = (int*)wp;      wp += (((size_t)N * 4 + 15) & ~15ull);
    uint4* g_a     = (uint4*)wp;    wp += (size_t)(N + 1) * 16;   // +1: zero row for pads
    uint4* g_b     = (uint4*)wp;    wp += (size_t)(N + 1) * 16;
    float* pooled  = (float*)wp;    wp += NG * NC * 4;            // gcnt follows contiguously
    float* gcnt    = (float*)wp;    wp += (((size_t)NG * 4 + 15) & ~15ull);
    int* ell       = (int*)wp;      wp += (size_t)N * SLOTS * 4;
    unsigned int* bucket_arr = (unsigned int*)wp;  wp += (size_t)nbk * BCAP * 4;

    const int BT = 256;
    int bn8 = ((size_t)N * 8 + BT - 1) / BT;
    int bn4 = ((size_t)N * 4 + BT - 1) / BT;
    int bp1 = (E + EPB - 1) / EPB;

    init_kernel<<<(NBK_MAX + 8 + NG * NC + NG + BT - 1) / BT, BT, 0, stream>>>(bucket_cursor, pooled);

    bucket_scatter_kernel<<<bp1, 512, 0, stream>>>(src, dst, E, nbk, bucket_cursor,
                                                   bucket_arr, bovf_meta, bovf);
    ell_build_kernel<<<nbk, 512, 0, stream>>>(bucket_arr, bucket_cursor, bovf_meta, bovf,
                                              ell, cnt, ovf_meta, ovf_dst, ovf_src, N);

    layer1_kernel<<<bn8, BT, 0, stream>>>(x, W[0], cnt, g_a, N);

    // 5 mid layers: (b1,W2) .. (b5,W6), alternating g buffers
    gcn_layer4_kernel<0><<<bn4, BT, 0, stream>>>(cnt, ell, ovf_meta, ovf_dst, ovf_src, g_a, g_b, W[1], b[0], N);
    gcn_layer4_kernel<0><<<bn4, BT, 0, stream>>>(cnt, ell, ovf_meta, ovf_dst, ovf_src, g_b, g_a, W[2], b[1], N);
    gcn_layer4_kernel<0><<<bn4, BT, 0, stream>>>(cnt, ell, ovf_meta, ovf_dst, ovf_src, g_a, g_b, W[3], b[2], N);
    gcn_layer4_kernel<0><<<bn4, BT, 0, stream>>>(cnt, ell, ovf_meta, ovf_dst, ovf_src, g_b, g_a, W[4], b[3], N);
    gcn_layer4_kernel<0><<<bn4, BT, 0, stream>>>(cnt, ell, ovf_meta, ovf_dst, ovf_src, g_a, g_b, W[5], b[4], N);
    // layer 6 epilogue (b6), no next W
    gcn_layer4_kernel<1><<<bn4, BT, 0, stream>>>(cnt, ell, ovf_meta, ovf_dst, ovf_src, g_b, g_a, nullptr, b[5], N);
    // conv7 gather + Wf + bf + relu + pool
    pool_kernel<<<bn4, BT, 0, stream>>>(cnt, ell, ovf_meta, ovf_dst, ovf_src, g_a, batch, W[6], b[6], pooled, gcnt, N);
    logsm_kernel<<<1, 64, 0, stream>>>(pooled, gcnt, out);
}